// Round 1
// baseline (3761.013 us; speedup 1.0000x reference)
//
#include <hip/hip_runtime.h>
#include <hip/hip_bf16.h>
#include <math.h>

static constexpr int L_ = 2, H_ = 12, DK_ = 64, DV_ = 64, D_ = 768,
                     DH_ = 3072, V_ = 32000, S_ = 1024, B_ = 2;
static constexpr int M_ = B_ * S_;  // 2048 token rows

// ---------------------------------------------------------------------------
// h[b,s,:] = emb[x[b,s],:] + pos[s,:] * (ignore[b,s]==0)
// ---------------------------------------------------------------------------
__global__ __launch_bounds__(256) void embed_kernel(
    const int* __restrict__ x, const int* __restrict__ ign,
    const float* __restrict__ emb, const float* __restrict__ pos,
    float* __restrict__ h)
{
    const int row = blockIdx.x;          // b*S + s
    const int s = row & (S_ - 1);
    const int tok = x[row];
    const float keep = (ign[row] == 0) ? 1.0f : 0.0f;
    const float* er = emb + (size_t)tok * D_;
    const float* pr = pos + (size_t)s * D_;
    float* hr = h + (size_t)row * D_;
    for (int d = threadIdx.x; d < D_; d += 256)
        hr[d] = er[d] + pr[d] * keep;
}

// ---------------------------------------------------------------------------
// Generic tiled fp32 GEMM: C[M,N] = A[M,K] @ B[K,N] + bias[N]; act=1 -> exact GELU
// BM=BN=64, BK=16, 256 threads, 4x4 micro-tile per thread.
// M,N multiples of 64; K multiple of 16 (all true for this problem).
// ---------------------------------------------------------------------------
__global__ __launch_bounds__(256) void gemm_kernel(
    const float* __restrict__ A, const float* __restrict__ Bm,
    const float* __restrict__ bias, float* __restrict__ C,
    int M, int N, int K, int act)
{
    __shared__ float As[16][68];   // [k][m], padded for float4 alignment
    __shared__ float Bs[16][64];   // [k][n]
    const int tid = threadIdx.x;
    const int bm = blockIdx.y * 64;
    const int bn = blockIdx.x * 64;
    const int tr = tid >> 4, tc = tid & 15;
    const int arow = tid >> 2, acol = (tid & 3) * 4;
    const int brow = tid >> 4, bcol = (tid & 15) * 4;
    float acc[4][4] = {};
    for (int k0 = 0; k0 < K; k0 += 16) {
        const float4 av = *(const float4*)(A + (size_t)(bm + arow) * K + k0 + acol);
        const float4 bv = *(const float4*)(Bm + (size_t)(k0 + brow) * N + bn + bcol);
        As[acol + 0][arow] = av.x;
        As[acol + 1][arow] = av.y;
        As[acol + 2][arow] = av.z;
        As[acol + 3][arow] = av.w;
        *(float4*)(&Bs[brow][bcol]) = bv;
        __syncthreads();
        #pragma unroll
        for (int kk = 0; kk < 16; ++kk) {
            const float* ap = &As[kk][tr * 4];
            const float* bp = &Bs[kk][tc * 4];
            #pragma unroll
            for (int i = 0; i < 4; ++i)
                #pragma unroll
                for (int j = 0; j < 4; ++j)
                    acc[i][j] = fmaf(ap[i], bp[j], acc[i][j]);
        }
        __syncthreads();
    }
    #pragma unroll
    for (int i = 0; i < 4; ++i) {
        const int m = bm + tr * 4 + i;
        #pragma unroll
        for (int j = 0; j < 4; ++j) {
            const int n = bn + tc * 4 + j;
            float v = acc[i][j] + bias[n];
            if (act == 1) v = 0.5f * v * (1.0f + erff(v * 0.70710678118654752f));
            C[(size_t)m * N + n] = v;
        }
    }
}

// ---------------------------------------------------------------------------
// Per-head QKV projection. W layout per layer: (H, D, 64) -> head slice is a
// contiguous 768x64 row-major matrix. Output layout (B, H, S, 64).
// grid: (M/64, H)
// ---------------------------------------------------------------------------
__global__ __launch_bounds__(256) void gemm_qkv_kernel(
    const float* __restrict__ A, const float* __restrict__ W,
    const float* __restrict__ bias, float* __restrict__ out)
{
    const int hh = blockIdx.y;
    const float* Bm = W + (size_t)hh * D_ * DK_;
    __shared__ float As[16][68];
    __shared__ float Bs[16][64];
    const int tid = threadIdx.x;
    const int bm = blockIdx.x * 64;
    const int tr = tid >> 4, tc = tid & 15;
    const int arow = tid >> 2, acol = (tid & 3) * 4;
    const int brow = tid >> 4, bcol = (tid & 15) * 4;
    float acc[4][4] = {};
    for (int k0 = 0; k0 < D_; k0 += 16) {
        const float4 av = *(const float4*)(A + (size_t)(bm + arow) * D_ + k0 + acol);
        const float4 bv = *(const float4*)(Bm + (size_t)(k0 + brow) * DK_ + bcol);
        As[acol + 0][arow] = av.x;
        As[acol + 1][arow] = av.y;
        As[acol + 2][arow] = av.z;
        As[acol + 3][arow] = av.w;
        *(float4*)(&Bs[brow][bcol]) = bv;
        __syncthreads();
        #pragma unroll
        for (int kk = 0; kk < 16; ++kk) {
            const float* ap = &As[kk][tr * 4];
            const float* bp = &Bs[kk][tc * 4];
            #pragma unroll
            for (int i = 0; i < 4; ++i)
                #pragma unroll
                for (int j = 0; j < 4; ++j)
                    acc[i][j] = fmaf(ap[i], bp[j], acc[i][j]);
        }
        __syncthreads();
    }
    #pragma unroll
    for (int i = 0; i < 4; ++i) {
        const int m = bm + tr * 4 + i;
        const int b = m >> 10;            // / S_
        const int s = m & (S_ - 1);
        #pragma unroll
        for (int j = 0; j < 4; ++j) {
            const int n = tc * 4 + j;
            out[(((size_t)b * H_ + hh) * S_ + s) * DK_ + n] = acc[i][j] + bias[hh * DK_ + n];
        }
    }
}

// ---------------------------------------------------------------------------
// Attention for one (b, h, query-row i). q,k,v layout (B,H,S,64).
// mask: j<=i AND (ignore[b,j]==0 OR j==i). Output sa layout (B, S, H*64).
// grid: (S, H, B), 256 threads.
// ---------------------------------------------------------------------------
__global__ __launch_bounds__(256) void attn_kernel(
    const float* __restrict__ q, const float* __restrict__ k,
    const float* __restrict__ v, const int* __restrict__ ign,
    float* __restrict__ sa)
{
    const int i = blockIdx.x, hh = blockIdx.y, b = blockIdx.z;
    const int tid = threadIdx.x;
    __shared__ float qs[64];
    __shared__ float sc[S_];
    __shared__ float red[256];
    __shared__ float pv[4][64];
    const size_t bh = ((size_t)b * H_ + hh) * S_;

    if (tid < 64) qs[tid] = q[(bh + i) * 64 + tid];
    __syncthreads();

    for (int j = tid; j <= i; j += 256) {
        float s_;
        if (ign[b * S_ + j] == 0 || j == i) {
            const float4* kr = (const float4*)(k + (bh + j) * 64);
            float d = 0.f;
            #pragma unroll
            for (int t = 0; t < 16; ++t) {
                const float4 kv = kr[t];
                d += qs[4 * t + 0] * kv.x + qs[4 * t + 1] * kv.y +
                     qs[4 * t + 2] * kv.z + qs[4 * t + 3] * kv.w;
            }
            s_ = d * 0.125f;   // / sqrt(64)
        } else {
            s_ = -INFINITY;
        }
        sc[j] = s_;
    }
    __syncthreads();

    float lmax = -INFINITY;
    for (int j = tid; j <= i; j += 256) lmax = fmaxf(lmax, sc[j]);
    red[tid] = lmax; __syncthreads();
    for (int o = 128; o; o >>= 1) {
        if (tid < o) red[tid] = fmaxf(red[tid], red[tid + o]);
        __syncthreads();
    }
    const float mx = red[0];
    __syncthreads();

    float lsum = 0.f;
    for (int j = tid; j <= i; j += 256) {
        const float p = __expf(sc[j] - mx);
        sc[j] = p;
        lsum += p;
    }
    red[tid] = lsum; __syncthreads();
    for (int o = 128; o; o >>= 1) {
        if (tid < o) red[tid] += red[tid + o];
        __syncthreads();
    }
    const float inv = 1.0f / red[0];

    const int g = tid >> 6, lane = tid & 63;
    float acc = 0.f;
    for (int j = g; j <= i; j += 4)
        acc = fmaf(sc[j], v[(bh + j) * 64 + lane], acc);
    pv[g][lane] = acc;
    __syncthreads();
    if (tid < 64) {
        const float r = (pv[0][tid] + pv[1][tid] + pv[2][tid] + pv[3][tid]) * inv;
        sa[((size_t)b * S_ + i) * (H_ * DV_) + hh * DV_ + tid] = r;
    }
}

// ---------------------------------------------------------------------------
// out[row,:] = LayerNorm(X[row,:] + Y[row,:])  (mean/biased-std, no eps, no affine)
// ---------------------------------------------------------------------------
__global__ __launch_bounds__(256) void add_ln_kernel(
    const float* __restrict__ X, const float* __restrict__ Y,
    float* __restrict__ out)
{
    const int row = blockIdx.x;
    const int tid = threadIdx.x;
    __shared__ float buf[D_];
    __shared__ float red[256];
    const float* xr = X + (size_t)row * D_;
    const float* yr = Y + (size_t)row * D_;
    float s0 = 0.f;
    for (int d = tid; d < D_; d += 256) {
        const float t = xr[d] + yr[d];
        buf[d] = t;
        s0 += t;
    }
    red[tid] = s0; __syncthreads();
    for (int o = 128; o; o >>= 1) {
        if (tid < o) red[tid] += red[tid + o];
        __syncthreads();
    }
    const float mu = red[0] * (1.0f / D_);
    __syncthreads();
    float s1 = 0.f;
    for (int d = tid; d < D_; d += 256) {
        const float t = buf[d] - mu;
        s1 += t * t;
    }
    red[tid] = s1; __syncthreads();
    for (int o = 128; o; o >>= 1) {
        if (tid < o) red[tid] += red[tid + o];
        __syncthreads();
    }
    const float inv = 1.0f / sqrtf(red[0] * (1.0f / D_));
    float* orow = out + (size_t)row * D_;
    for (int d = tid; d < D_; d += 256)
        orow[d] = (buf[d] - mu) * inv;
}

// ---------------------------------------------------------------------------
extern "C" void kernel_launch(void* const* d_in, const int* in_sizes, int n_in,
                              void* d_out, int out_size, void* d_ws, size_t ws_size,
                              hipStream_t stream)
{
    const int*   x    = (const int*)d_in[0];
    const int*   ign  = (const int*)d_in[1];
    const float* emb  = (const float*)d_in[2];
    const float* pos  = (const float*)d_in[3];
    const float* Wq   = (const float*)d_in[4];
    const float* bq   = (const float*)d_in[5];
    const float* Wk   = (const float*)d_in[6];
    const float* bk   = (const float*)d_in[7];
    const float* Wv   = (const float*)d_in[8];
    const float* bv   = (const float*)d_in[9];
    const float* Wo   = (const float*)d_in[10];
    const float* bo   = (const float*)d_in[11];
    const float* W1   = (const float*)d_in[12];
    const float* b1   = (const float*)d_in[13];
    const float* W2   = (const float*)d_in[14];
    const float* b2   = (const float*)d_in[15];
    const float* Wout = (const float*)d_in[16];
    const float* bout = (const float*)d_in[17];
    float* outp = (float*)d_out;

    const size_t RC = (size_t)M_ * D_;        // 1.57M floats per (M,768) buffer
    float* ws  = (float*)d_ws;
    float* h   = ws;
    float* z   = h + RC;
    float* qb  = z + RC;
    float* kb  = qb + RC;
    float* vb  = kb + RC;
    float* sab = vb + RC;
    float* tmp = sab + RC;
    const size_t needF1 = (size_t)M_ * DH_;   // 6.29M floats
    float* f1;
    if (ws_size >= (7 * RC + needF1) * sizeof(float)) {
        f1 = tmp + RC;
    } else {
        // d_out (65.5M f32) as scratch: f1 is dead before the final GEMM
        // overwrites the whole output buffer.
        f1 = outp;
    }

    embed_kernel<<<M_, 256, 0, stream>>>(x, ign, emb, pos, h);

    for (int l = 0; l < L_; ++l) {
        const float* Wql = Wq + (size_t)l * H_ * D_ * DK_;
        const float* bql = bq + (size_t)l * H_ * DK_;
        const float* Wkl = Wk + (size_t)l * H_ * D_ * DK_;
        const float* bkl = bk + (size_t)l * H_ * DK_;
        const float* Wvl = Wv + (size_t)l * H_ * D_ * DV_;
        const float* bvl = bv + (size_t)l * H_ * DV_;
        const float* Wol = Wo + (size_t)l * (H_ * DV_) * D_;
        const float* bol = bo + (size_t)l * D_;
        const float* W1l = W1 + (size_t)l * D_ * DH_;
        const float* b1l = b1 + (size_t)l * DH_;
        const float* W2l = W2 + (size_t)l * DH_ * D_;
        const float* b2l = b2 + (size_t)l * D_;

        gemm_qkv_kernel<<<dim3(M_ / 64, H_), 256, 0, stream>>>(h, Wql, bql, qb);
        gemm_qkv_kernel<<<dim3(M_ / 64, H_), 256, 0, stream>>>(h, Wkl, bkl, kb);
        gemm_qkv_kernel<<<dim3(M_ / 64, H_), 256, 0, stream>>>(h, Wvl, bvl, vb);

        attn_kernel<<<dim3(S_, H_, B_), 256, 0, stream>>>(qb, kb, vb, ign, sab);

        gemm_kernel<<<dim3(D_ / 64, M_ / 64), 256, 0, stream>>>(
            sab, Wol, bol, tmp, M_, D_, D_, 0);
        add_ln_kernel<<<M_, 256, 0, stream>>>(h, tmp, z);

        gemm_kernel<<<dim3(DH_ / 64, M_ / 64), 256, 0, stream>>>(
            z, W1l, b1l, f1, M_, DH_, D_, 0);
        gemm_kernel<<<dim3(D_ / 64, M_ / 64), 256, 0, stream>>>(
            f1, W2l, b2l, tmp, M_, D_, DH_, 1);
        add_ln_kernel<<<M_, 256, 0, stream>>>(z, tmp, h);
    }

    gemm_kernel<<<dim3(V_ / 64, M_ / 64), 256, 0, stream>>>(
        h, Wout, bout, outp, M_, V_, D_, 0);
}

// Round 2
// 2095.642 us; speedup vs baseline: 1.7947x; 1.7947x over previous
//
#include <hip/hip_runtime.h>
#include <math.h>

static constexpr int L_ = 2, H_ = 12, DK_ = 64, DV_ = 64, D_ = 768,
                     DH_ = 3072, V_ = 32000, S_ = 1024, B_ = 2;
static constexpr int M_ = B_ * S_;  // 2048 token rows

typedef __attribute__((ext_vector_type(4))) float f32x4;
typedef __attribute__((ext_vector_type(8))) short s16x8;   // 8 bf16 = 4 VGPR
typedef __attribute__((ext_vector_type(2))) unsigned int u32x2;

__device__ __forceinline__ unsigned short f2bf(float f) {
    unsigned u = __builtin_bit_cast(unsigned, f);
    u = (u + 0x7FFFu + ((u >> 16) & 1u)) >> 16;   // RTNE
    return (unsigned short)u;
}

__device__ __forceinline__ void gld16(const void* g, void* l) {
    __builtin_amdgcn_global_load_lds(
        (const __attribute__((address_space(1))) unsigned int*)g,
        (__attribute__((address_space(3))) unsigned int*)l, 16, 0, 0);
}

// ---------------------------------------------------------------------------
// bf16 MFMA GEMM: C[M,N] = A[M,K](bf16) @ B[K,N](fp32 weights) + bias
// A staged via global_load_lds (swizzled source); B reg-staged with in-kernel
// fp32->bf16 convert + 4x4 transpose into k-contiguous swizzled LDS.
// bmode 0: B row-major [K][N]. bmode 1: QKV weights [H][D][64], col n=h*64+dk.
// act 0: bias, f32 out. act 1: bias+exact GELU, f32 out. act 2: bias, bf16 out.
// tile 128x128, BK=64, 256 threads (4 waves 2x2), mfma_f32_16x16x32_bf16.
// ---------------------------------------------------------------------------
__device__ __forceinline__ void gemm_body(
    const unsigned short* __restrict__ A, const float* __restrict__ B,
    const float* __restrict__ bias, void* __restrict__ Cp,
    int M, int N, int K, int act, int bmode, int bx, int by)
{
    __shared__ unsigned short As[8192];   // [row 128][k 64] bf16, swizzled granules
    __shared__ unsigned short Bs[8192];   // [col 128][k 64] bf16, swizzled granules
    const int tid = threadIdx.x;
    const int l   = tid & 63, wid = tid >> 6;
    const int wr  = wid >> 1, wc = wid & 1;
    const int brow = by * 128, bn = bx * 128;

    f32x4 acc[4][4];
    #pragma unroll
    for (int i = 0; i < 4; ++i)
        #pragma unroll
        for (int j = 0; j < 4; ++j) acc[i][j] = (f32x4)0.f;

    const int arow = tid >> 3;                      // 0..31 per round
    const int aq   = (tid & 7) ^ (arow & 7);        // inverse-swizzled source granule
    const int bkq  = tid >> 5;                      // 0..7
    const int bnq  = tid & 31;                      // n-quad

    for (int k0 = 0; k0 < K; k0 += 64) {
        // ---- stage A: 4 x global_load_lds, 16B/lane, linear LDS dest
        #pragma unroll
        for (int r = 0; r < 4; ++r) {
            const unsigned short* src =
                A + (size_t)(brow + r * 32 + arow) * K + (k0 + aq * 8);
            gld16(src, (char*)As + (r * 4096 + wid * 1024));
        }
        // ---- stage B: 2 rounds: 4x float4 load, cvt, 4x ds_write_b64 (transposed)
        #pragma unroll
        for (int r = 0; r < 2; ++r) {
            const int kb = r * 32 + bkq * 4;        // local k base (4-aligned)
            float4 v0, v1, v2, v3;
            if (bmode == 0) {
                const float* p = B + (size_t)(k0 + kb) * N + bn + bnq * 4;
                v0 = *(const float4*)(p);
                v1 = *(const float4*)(p + N);
                v2 = *(const float4*)(p + 2 * (size_t)N);
                v3 = *(const float4*)(p + 3 * (size_t)N);
            } else {
                const int n = bn + bnq * 4;
                const float* p = B + ((size_t)(n >> 6) * D_ + (k0 + kb)) * 64 + (n & 63);
                v0 = *(const float4*)(p);
                v1 = *(const float4*)(p + 64);
                v2 = *(const float4*)(p + 128);
                v3 = *(const float4*)(p + 192);
            }
            const int g     = kb >> 3;              // k-granule
            const int bytek = (kb & 4) * 2;         // 0 or 8 within granule
            const float* f0 = (const float*)&v0;
            const float* f1 = (const float*)&v1;
            const float* f2 = (const float*)&v2;
            const float* f3 = (const float*)&v3;
            #pragma unroll
            for (int i = 0; i < 4; ++i) {
                const int n = bnq * 4 + i;
                const unsigned lo = (unsigned)f2bf(f0[i]) | ((unsigned)f2bf(f1[i]) << 16);
                const unsigned hi = (unsigned)f2bf(f2[i]) | ((unsigned)f2bf(f3[i]) << 16);
                char* dst = (char*)Bs + n * 128 + ((g ^ (n & 7)) * 16) + bytek;
                *(u32x2*)dst = (u32x2){lo, hi};
            }
        }
        __syncthreads();

        // ---- compute: 2 k-subtiles x (8 ds_read_b128 + 16 MFMA)
        #pragma unroll
        for (int kk = 0; kk < 2; ++kk) {
            s16x8 af[4], bf[4];
            #pragma unroll
            for (int mf = 0; mf < 4; ++mf) {
                const int row = wr * 64 + mf * 16 + (l & 15);
                const int gg  = (kk * 4 + (l >> 4)) ^ (row & 7);
                af[mf] = *(const s16x8*)((const char*)As + row * 128 + gg * 16);
            }
            #pragma unroll
            for (int nf = 0; nf < 4; ++nf) {
                const int col = wc * 64 + nf * 16 + (l & 15);
                const int gg  = (kk * 4 + (l >> 4)) ^ (col & 7);
                bf[nf] = *(const s16x8*)((const char*)Bs + col * 128 + gg * 16);
            }
            #pragma unroll
            for (int mf = 0; mf < 4; ++mf)
                #pragma unroll
                for (int nf = 0; nf < 4; ++nf)
                    acc[mf][nf] = __builtin_amdgcn_mfma_f32_16x16x32_bf16(
                        af[mf], bf[nf], acc[mf][nf], 0, 0, 0);
        }
        __syncthreads();
    }

    // ---- epilogue: C/D layout col=l&15, row=(l>>4)*4+reg
    const int lr = l >> 4, lc = l & 15;
    #pragma unroll
    for (int nf = 0; nf < 4; ++nf) {
        const int gcol = bn + wc * 64 + nf * 16 + lc;
        const float bb = bias[gcol];
        #pragma unroll
        for (int mf = 0; mf < 4; ++mf) {
            #pragma unroll
            for (int rg = 0; rg < 4; ++rg) {
                const int grow = brow + wr * 64 + mf * 16 + lr * 4 + rg;
                float vv = acc[mf][nf][rg] + bb;
                if (act == 1) vv = 0.5f * vv * (1.0f + erff(vv * 0.70710678118654752f));
                if (act == 2)
                    ((unsigned short*)Cp)[(size_t)grow * N + gcol] = f2bf(vv);
                else
                    ((float*)Cp)[(size_t)grow * N + gcol] = vv;
            }
        }
    }
}

__global__ __launch_bounds__(256) void gemm_main(
    const unsigned short* __restrict__ A, const float* __restrict__ B,
    const float* __restrict__ bias, void* __restrict__ C,
    int M, int N, int K, int act, int bmode)
{
    gemm_body(A, B, bias, C, M, N, K, act, bmode, blockIdx.x, blockIdx.y);
}

__global__ __launch_bounds__(256) void gemm_qkv3(
    const unsigned short* __restrict__ A,
    const float* __restrict__ Wq, const float* __restrict__ Wk, const float* __restrict__ Wv,
    const float* __restrict__ bq, const float* __restrict__ bk, const float* __restrict__ bv,
    float* __restrict__ q, float* __restrict__ k, float* __restrict__ v,
    int M, int N, int K)
{
    const float* B; const float* bi; float* C;
    if (blockIdx.z == 0)      { B = Wq; bi = bq; C = q; }
    else if (blockIdx.z == 1) { B = Wk; bi = bk; C = k; }
    else                      { B = Wv; bi = bv; C = v; }
    gemm_body(A, B, bi, C, M, N, K, 0, 1, blockIdx.x, blockIdx.y);
}

// ---------------------------------------------------------------------------
// h = emb[x] + pos * (ignore==0); writes fp32 h and bf16 hbf
// ---------------------------------------------------------------------------
__global__ __launch_bounds__(256) void embed_kernel(
    const int* __restrict__ x, const int* __restrict__ ign,
    const float* __restrict__ emb, const float* __restrict__ pos,
    float* __restrict__ h, unsigned short* __restrict__ hbf)
{
    const int row = blockIdx.x;
    const int s = row & (S_ - 1);
    const int tok = x[row];
    const float keep = (ign[row] == 0) ? 1.0f : 0.0f;
    const float* er = emb + (size_t)tok * D_;
    const float* pr = pos + (size_t)s * D_;
    float* hr = h + (size_t)row * D_;
    unsigned short* hb = hbf + (size_t)row * D_;
    for (int d = threadIdx.x; d < D_; d += 256) {
        const float t = er[d] + pr[d] * keep;
        hr[d] = t;
        hb[d] = f2bf(t);
    }
}

// ---------------------------------------------------------------------------
// Attention, fp32. q,k,v layout [M][H*64] (col = h*64+d). Output sab bf16 same layout.
// mask: j<=i AND (ignore[b,j]==0 OR j==i). grid (S, H, B), 256 threads.
// ---------------------------------------------------------------------------
__global__ __launch_bounds__(256) void attn_kernel(
    const float* __restrict__ q, const float* __restrict__ k,
    const float* __restrict__ v, const int* __restrict__ ign,
    unsigned short* __restrict__ sab)
{
    const int i = blockIdx.x, hh = blockIdx.y, b = blockIdx.z;
    const int tid = threadIdx.x;
    __shared__ float qs[64];
    __shared__ float sc[S_];
    __shared__ float red[256];
    __shared__ float pv[4][64];

    if (tid < 64) qs[tid] = q[((size_t)b * S_ + i) * (H_ * 64) + hh * 64 + tid];
    __syncthreads();

    for (int j = tid; j <= i; j += 256) {
        float s_;
        if (ign[b * S_ + j] == 0 || j == i) {
            const float4* kr = (const float4*)(k + ((size_t)b * S_ + j) * (H_ * 64) + hh * 64);
            float d = 0.f;
            #pragma unroll
            for (int t = 0; t < 16; ++t) {
                const float4 kv = kr[t];
                d += qs[4 * t + 0] * kv.x + qs[4 * t + 1] * kv.y +
                     qs[4 * t + 2] * kv.z + qs[4 * t + 3] * kv.w;
            }
            s_ = d * 0.125f;
        } else {
            s_ = -INFINITY;
        }
        sc[j] = s_;
    }
    __syncthreads();

    float lmax = -INFINITY;
    for (int j = tid; j <= i; j += 256) lmax = fmaxf(lmax, sc[j]);
    red[tid] = lmax; __syncthreads();
    for (int o = 128; o; o >>= 1) {
        if (tid < o) red[tid] = fmaxf(red[tid], red[tid + o]);
        __syncthreads();
    }
    const float mx = red[0];
    __syncthreads();

    float lsum = 0.f;
    for (int j = tid; j <= i; j += 256) {
        const float p = __expf(sc[j] - mx);
        sc[j] = p;
        lsum += p;
    }
    red[tid] = lsum; __syncthreads();
    for (int o = 128; o; o >>= 1) {
        if (tid < o) red[tid] += red[tid + o];
        __syncthreads();
    }
    const float inv = 1.0f / red[0];

    const int g = tid >> 6, lane = tid & 63;
    float acc = 0.f;
    for (int j = g; j <= i; j += 4)
        acc = fmaf(sc[j], v[((size_t)b * S_ + j) * (H_ * 64) + hh * 64 + lane], acc);
    pv[g][lane] = acc;
    __syncthreads();
    if (tid < 64) {
        const float r = (pv[0][tid] + pv[1][tid] + pv[2][tid] + pv[3][tid]) * inv;
        sab[((size_t)b * S_ + i) * (H_ * 64) + hh * 64 + tid] = f2bf(r);
    }
}

// ---------------------------------------------------------------------------
// out = LayerNorm(X + Y) (biased std, no eps/affine); fp32 out + bf16 copy
// ---------------------------------------------------------------------------
__global__ __launch_bounds__(256) void add_ln_kernel(
    const float* __restrict__ X, const float* __restrict__ Y,
    float* __restrict__ out, unsigned short* __restrict__ outbf)
{
    const int row = blockIdx.x;
    const int tid = threadIdx.x;
    __shared__ float buf[D_];
    __shared__ float red[256];
    const float* xr = X + (size_t)row * D_;
    const float* yr = Y + (size_t)row * D_;
    float s0 = 0.f;
    for (int d = tid; d < D_; d += 256) {
        const float t = xr[d] + yr[d];
        buf[d] = t;
        s0 += t;
    }
    red[tid] = s0; __syncthreads();
    for (int o = 128; o; o >>= 1) {
        if (tid < o) red[tid] += red[tid + o];
        __syncthreads();
    }
    const float mu = red[0] * (1.0f / D_);
    __syncthreads();
    float s1 = 0.f;
    for (int d = tid; d < D_; d += 256) {
        const float t = buf[d] - mu;
        s1 += t * t;
    }
    red[tid] = s1; __syncthreads();
    for (int o = 128; o; o >>= 1) {
        if (tid < o) red[tid] += red[tid + o];
        __syncthreads();
    }
    const float inv = 1.0f / sqrtf(red[0] * (1.0f / D_));
    float* orow = out + (size_t)row * D_;
    unsigned short* obf = outbf + (size_t)row * D_;
    for (int d = tid; d < D_; d += 256) {
        const float t = (buf[d] - mu) * inv;
        orow[d] = t;
        obf[d] = f2bf(t);
    }
}

// ---------------------------------------------------------------------------
extern "C" void kernel_launch(void* const* d_in, const int* in_sizes, int n_in,
                              void* d_out, int out_size, void* d_ws, size_t ws_size,
                              hipStream_t stream)
{
    const int*   x    = (const int*)d_in[0];
    const int*   ign  = (const int*)d_in[1];
    const float* emb  = (const float*)d_in[2];
    const float* pos  = (const float*)d_in[3];
    const float* Wq   = (const float*)d_in[4];
    const float* bq   = (const float*)d_in[5];
    const float* Wk   = (const float*)d_in[6];
    const float* bk   = (const float*)d_in[7];
    const float* Wv   = (const float*)d_in[8];
    const float* bv   = (const float*)d_in[9];
    const float* Wo   = (const float*)d_in[10];
    const float* bo   = (const float*)d_in[11];
    const float* W1   = (const float*)d_in[12];
    const float* b1   = (const float*)d_in[13];
    const float* W2   = (const float*)d_in[14];
    const float* b2   = (const float*)d_in[15];
    const float* Wout = (const float*)d_in[16];
    const float* bout = (const float*)d_in[17];
    float* outp = (float*)d_out;

    const size_t RC = (size_t)M_ * D_;            // 1572864
    const size_t F1 = (size_t)M_ * DH_;           // 6291456
    // scratch: fp32 {h,z,tmp,q,k,v} + bf16 {zbf,sabbf,f1bf} (+hbf)
    const size_t need_all = 6 * RC * 4 + (3 * RC + F1 + RC) * 2 + 4096;
    const bool big = ws_size >= need_all;

    float* fbase = big ? (float*)d_ws : (float*)d_out;  // d_out scratch is dead
    float* h   = fbase;                                 // before final GEMM writes it
    float* z   = h + RC;
    float* tmp = z + RC;
    float* q   = tmp + RC;
    float* k   = q + RC;
    float* v   = k + RC;
    unsigned short* ubase = (unsigned short*)(v + RC);
    unsigned short* zbf   = ubase;
    unsigned short* sabbf = zbf + RC;
    unsigned short* f1bf  = sabbf + RC;
    // hbf is live during the final GEMM (A operand) -> must not be in d_out
    unsigned short* hbf = big ? (f1bf + F1) : (unsigned short*)d_ws;

    embed_kernel<<<M_, 256, 0, stream>>>(x, ign, emb, pos, h, hbf);

    for (int l = 0; l < L_; ++l) {
        const float* Wql = Wq + (size_t)l * H_ * D_ * DK_;
        const float* bql = bq + (size_t)l * H_ * DK_;
        const float* Wkl = Wk + (size_t)l * H_ * D_ * DK_;
        const float* bkl = bk + (size_t)l * H_ * DK_;
        const float* Wvl = Wv + (size_t)l * H_ * D_ * DV_;
        const float* bvl = bv + (size_t)l * H_ * DV_;
        const float* Wol = Wo + (size_t)l * (H_ * DV_) * D_;
        const float* bol = bo + (size_t)l * D_;
        const float* W1l = W1 + (size_t)l * D_ * DH_;
        const float* b1l = b1 + (size_t)l * DH_;
        const float* W2l = W2 + (size_t)l * DH_ * D_;
        const float* b2l = b2 + (size_t)l * D_;

        gemm_qkv3<<<dim3(6, 16, 3), 256, 0, stream>>>(
            hbf, Wql, Wkl, Wvl, bql, bkl, bvl, q, k, v, M_, 768, 768);

        attn_kernel<<<dim3(S_, H_, B_), 256, 0, stream>>>(q, k, v, ign, sabbf);

        gemm_main<<<dim3(6, 16), 256, 0, stream>>>(
            sabbf, Wol, bol, tmp, M_, 768, 768, 0, 0);
        add_ln_kernel<<<M_, 256, 0, stream>>>(h, tmp, z, zbf);

        gemm_main<<<dim3(24, 16), 256, 0, stream>>>(
            zbf, W1l, b1l, f1bf, M_, 3072, 768, 2, 0);
        gemm_main<<<dim3(6, 16), 256, 0, stream>>>(
            f1bf, W2l, b2l, tmp, M_, 768, 3072, 1, 0);
        add_ln_kernel<<<M_, 256, 0, stream>>>(z, tmp, h, hbf);
    }

    gemm_main<<<dim3(V_ / 128, M_ / 128), 256, 0, stream>>>(
        hbf, Wout, bout, outp, M_, V_, 768, 0, 0);
}

// Round 3
// 1025.188 us; speedup vs baseline: 3.6686x; 2.0442x over previous
//
#include <hip/hip_runtime.h>
#include <math.h>

static constexpr int L_ = 2, H_ = 12, D_ = 768, DH_ = 3072, V_ = 32000,
                     S_ = 1024, B_ = 2;
static constexpr int M_ = B_ * S_;  // 2048 token rows

typedef __attribute__((ext_vector_type(4))) float f32x4;
typedef __attribute__((ext_vector_type(8))) short s16x8;   // 8 bf16 = 4 VGPR
typedef __attribute__((ext_vector_type(2))) unsigned int u32x2;

__device__ __forceinline__ unsigned short f2bf(float f) {
    unsigned u = __builtin_bit_cast(unsigned, f);
    u = (u + 0x7FFFu + ((u >> 16) & 1u)) >> 16;   // RTNE
    return (unsigned short)u;
}
__device__ __forceinline__ unsigned pack2(float a, float b) {
    return (unsigned)f2bf(a) | ((unsigned)f2bf(b) << 16);
}

__device__ __forceinline__ void gld16(const void* g, void* l) {
    __builtin_amdgcn_global_load_lds(
        (const __attribute__((address_space(1))) unsigned int*)g,
        (__attribute__((address_space(3))) unsigned int*)l, 16, 0, 0);
}

// ---------------------------------------------------------------------------
// bf16 MFMA GEMM: C[M,N] = A[M,K](bf16) @ B[K,N](fp32 weights) + bias
// bmode 0: B row-major [K][N]. bmode 1: QKV weights [H][D][64], col n=h*64+dk.
// act 0: f32 out. act 1: f32 + exact GELU. act 2: bf16 out [M][N].
// act 3: bf16 out V-transposed [B][H][64][S].
// tile 128x128, BK=64, 256 threads (4 waves 2x2), mfma_f32_16x16x32_bf16.
// ---------------------------------------------------------------------------
__device__ __forceinline__ void gemm_body(
    const unsigned short* __restrict__ A, const float* __restrict__ B,
    const float* __restrict__ bias, void* __restrict__ Cp,
    int M, int N, int K, int act, int bmode, int bx, int by)
{
    __shared__ unsigned short As[8192];   // [row 128][k 64] bf16, swizzled granules
    __shared__ unsigned short Bs[8192];   // [col 128][k 64] bf16, swizzled granules
    const int tid = threadIdx.x;
    const int l   = tid & 63, wid = tid >> 6;
    const int wr  = wid >> 1, wc = wid & 1;
    const int brow = by * 128, bn = bx * 128;

    f32x4 acc[4][4];
    #pragma unroll
    for (int i = 0; i < 4; ++i)
        #pragma unroll
        for (int j = 0; j < 4; ++j) acc[i][j] = (f32x4)0.f;

    const int arow = tid >> 3;                      // 0..31 per round
    const int aq   = (tid & 7) ^ (arow & 7);        // inverse-swizzled source granule
    const int bkq  = tid >> 5;                      // 0..7
    const int bnq  = tid & 31;                      // n-quad

    for (int k0 = 0; k0 < K; k0 += 64) {
        #pragma unroll
        for (int r = 0; r < 4; ++r) {
            const unsigned short* src =
                A + (size_t)(brow + r * 32 + arow) * K + (k0 + aq * 8);
            gld16(src, (char*)As + (r * 4096 + wid * 1024));
        }
        #pragma unroll
        for (int r = 0; r < 2; ++r) {
            const int kb = r * 32 + bkq * 4;
            float4 v0, v1, v2, v3;
            if (bmode == 0) {
                const float* p = B + (size_t)(k0 + kb) * N + bn + bnq * 4;
                v0 = *(const float4*)(p);
                v1 = *(const float4*)(p + N);
                v2 = *(const float4*)(p + 2 * (size_t)N);
                v3 = *(const float4*)(p + 3 * (size_t)N);
            } else {
                const int n = bn + bnq * 4;
                const float* p = B + ((size_t)(n >> 6) * D_ + (k0 + kb)) * 64 + (n & 63);
                v0 = *(const float4*)(p);
                v1 = *(const float4*)(p + 64);
                v2 = *(const float4*)(p + 128);
                v3 = *(const float4*)(p + 192);
            }
            const int g     = kb >> 3;
            const int bytek = (kb & 4) * 2;
            const float* f0 = (const float*)&v0;
            const float* f1 = (const float*)&v1;
            const float* f2 = (const float*)&v2;
            const float* f3 = (const float*)&v3;
            #pragma unroll
            for (int i = 0; i < 4; ++i) {
                const int n = bnq * 4 + i;
                const unsigned lo = (unsigned)f2bf(f0[i]) | ((unsigned)f2bf(f1[i]) << 16);
                const unsigned hi = (unsigned)f2bf(f2[i]) | ((unsigned)f2bf(f3[i]) << 16);
                char* dst = (char*)Bs + n * 128 + ((g ^ (n & 7)) * 16) + bytek;
                *(u32x2*)dst = (u32x2){lo, hi};
            }
        }
        __syncthreads();

        #pragma unroll
        for (int kk = 0; kk < 2; ++kk) {
            s16x8 af[4], bf[4];
            #pragma unroll
            for (int mf = 0; mf < 4; ++mf) {
                const int row = wr * 64 + mf * 16 + (l & 15);
                const int gg  = (kk * 4 + (l >> 4)) ^ (row & 7);
                af[mf] = *(const s16x8*)((const char*)As + row * 128 + gg * 16);
            }
            #pragma unroll
            for (int nf = 0; nf < 4; ++nf) {
                const int col = wc * 64 + nf * 16 + (l & 15);
                const int gg  = (kk * 4 + (l >> 4)) ^ (col & 7);
                bf[nf] = *(const s16x8*)((const char*)Bs + col * 128 + gg * 16);
            }
            #pragma unroll
            for (int mf = 0; mf < 4; ++mf)
                #pragma unroll
                for (int nf = 0; nf < 4; ++nf)
                    acc[mf][nf] = __builtin_amdgcn_mfma_f32_16x16x32_bf16(
                        af[mf], bf[nf], acc[mf][nf], 0, 0, 0);
        }
        __syncthreads();
    }

    const int lr = l >> 4, lc = l & 15;
    #pragma unroll
    for (int nf = 0; nf < 4; ++nf) {
        const int gcol = bn + wc * 64 + nf * 16 + lc;
        const float bb = bias[gcol];
        #pragma unroll
        for (int mf = 0; mf < 4; ++mf) {
            if (act == 3) {
                const int grow0 = brow + wr * 64 + mf * 16 + lr * 4;
                const int b = grow0 >> 10, s0 = grow0 & (S_ - 1);
                const int head = gcol >> 6, d = gcol & 63;
                u32x2 pk;
                pk[0] = pack2(acc[mf][nf][0] + bb, acc[mf][nf][1] + bb);
                pk[1] = pack2(acc[mf][nf][2] + bb, acc[mf][nf][3] + bb);
                unsigned short* dst = (unsigned short*)Cp +
                    (((size_t)b * H_ + head) * 64 + d) * S_ + s0;
                *(u32x2*)dst = pk;
            } else {
                #pragma unroll
                for (int rg = 0; rg < 4; ++rg) {
                    const int grow = brow + wr * 64 + mf * 16 + lr * 4 + rg;
                    float vv = acc[mf][nf][rg] + bb;
                    if (act == 1) vv = 0.5f * vv * (1.0f + erff(vv * 0.70710678118654752f));
                    if (act == 2)
                        ((unsigned short*)Cp)[(size_t)grow * N + gcol] = f2bf(vv);
                    else
                        ((float*)Cp)[(size_t)grow * N + gcol] = vv;
                }
            }
        }
    }
}

__global__ __launch_bounds__(256) void gemm_main(
    const unsigned short* __restrict__ A, const float* __restrict__ B,
    const float* __restrict__ bias, void* __restrict__ C,
    int M, int N, int K, int act, int bmode)
{
    gemm_body(A, B, bias, C, M, N, K, act, bmode, blockIdx.x, blockIdx.y);
}

__global__ __launch_bounds__(256) void gemm_qkv3(
    const unsigned short* __restrict__ A,
    const float* __restrict__ Wq, const float* __restrict__ Wk, const float* __restrict__ Wv,
    const float* __restrict__ bq, const float* __restrict__ bk, const float* __restrict__ bv,
    unsigned short* __restrict__ q, unsigned short* __restrict__ k,
    unsigned short* __restrict__ v, int M, int N, int K)
{
    const float* B; const float* bi; unsigned short* C; int act;
    if (blockIdx.z == 0)      { B = Wq; bi = bq; C = q; act = 2; }
    else if (blockIdx.z == 1) { B = Wk; bi = bk; C = k; act = 2; }
    else                      { B = Wv; bi = bv; C = v; act = 3; }
    gemm_body(A, B, bi, C, M, N, K, act, 1, blockIdx.x, blockIdx.y);
}

// ---------------------------------------------------------------------------
// Flash attention. q,k: bf16 [M][768] (col=h*64+dk). vt: bf16 [B][H][64][S].
// mask: j<=i AND (ignore[b,j]==0 OR j==i). Output sab bf16 [M][768].
// grid (S/64, H, B), 256 threads = 4 waves; wave owns 16 q-rows (Q in regs).
// Swapped QK^T (mfma(K,Q) -> S^T, q-row lane-local): softmax = 16 in-lane +
// 2 shfl_xor. P^T repacked bf16 via per-wave swizzled LDS; O^T += V^T @ P^T.
// ---------------------------------------------------------------------------
__global__ __launch_bounds__(256) void fattn_kernel(
    const unsigned short* __restrict__ qm, const unsigned short* __restrict__ km,
    const unsigned short* __restrict__ vt, const int* __restrict__ ign,
    unsigned short* __restrict__ sab)
{
    __shared__ unsigned short Ks[4096];    // [key 64][k 64] bf16, swizzled granules
    __shared__ unsigned short VTs[4096];   // [d 64][key 64] bf16, swizzled granules
    __shared__ int igns[64];
    __shared__ unsigned short PTs[4][1024]; // per-wave [q 16][key 64], swizzled

    const int qt = blockIdx.x, hh = blockIdx.y, b = blockIdx.z;
    const int tid = threadIdx.x;
    const int l = tid & 63, w = tid >> 6;
    const int g = l >> 4, lq = l & 15;
    const int qb = qt * 64;
    const int i = qb + w * 16 + lq;          // this lane's query row

    const size_t qgb = ((size_t)(b * S_ + i)) * D_ + hh * 64;
    const s16x8 qf0 = *(const s16x8*)(qm + qgb + g * 8);
    const s16x8 qf1 = *(const s16x8*)(qm + qgb + 32 + g * 8);

    f32x4 accO[4];
    #pragma unroll
    for (int d = 0; d < 4; ++d) accO[d] = (f32x4)0.f;
    float mrun = -1e30f, lrun = 0.f;

    const int srow = tid >> 3, sg = tid & 7;   // staging: 8 granules per row

    for (int t = 0; t <= qt; ++t) {
        const int j0 = t * 64;
        #pragma unroll
        for (int r = 0; r < 2; ++r) {
            const int row = r * 32 + srow;
            const int gsw = (sg ^ (row & 7)) * 8;
            const unsigned short* ksrc =
                km + (size_t)(b * S_ + j0 + row) * D_ + hh * 64 + gsw;
            gld16(ksrc, (char*)Ks + (r * 256 + tid) * 16);
            const unsigned short* vsrc =
                vt + ((size_t)(b * H_ + hh) * 64 + row) * S_ + j0 + gsw;
            gld16(vsrc, (char*)VTs + (r * 256 + tid) * 16);
        }
        if (tid < 64) igns[tid] = ign[b * S_ + j0 + tid];
        __syncthreads();

        // ---- S^T = K @ Q^T : per lane, col = q-row (lq), rows = 16 keys
        f32x4 sacc[4];
        #pragma unroll
        for (int kf = 0; kf < 4; ++kf) sacc[kf] = (f32x4)0.f;
        #pragma unroll
        for (int kk = 0; kk < 2; ++kk) {
            const s16x8 qv = kk ? qf1 : qf0;
            #pragma unroll
            for (int kf = 0; kf < 4; ++kf) {
                const int row = kf * 16 + lq;
                const s16x8 kv = *(const s16x8*)((const char*)Ks + row * 128 +
                                                 (((kk * 4 + g) ^ (row & 7)) * 16));
                sacc[kf] = __builtin_amdgcn_mfma_f32_16x16x32_bf16(kv, qv, sacc[kf], 0, 0, 0);
            }
        }

        // ---- mask + online softmax (keys for this lane: kf*16 + g*4 + rg)
        float tmax = -INFINITY;
        #pragma unroll
        for (int kf = 0; kf < 4; ++kf)
            #pragma unroll
            for (int rg = 0; rg < 4; ++rg) {
                const int j = j0 + kf * 16 + g * 4 + rg;
                float s = sacc[kf][rg] * 0.125f;
                const bool ok = (j <= i) && (igns[kf * 16 + g * 4 + rg] == 0 || j == i);
                s = ok ? s : -INFINITY;
                sacc[kf][rg] = s;
                tmax = fmaxf(tmax, s);
            }
        tmax = fmaxf(tmax, __shfl_xor(tmax, 16));
        tmax = fmaxf(tmax, __shfl_xor(tmax, 32));
        const float mnew = fmaxf(mrun, tmax);
        const float fac = __expf(mrun - mnew);
        float psum = 0.f;
        #pragma unroll
        for (int kf = 0; kf < 4; ++kf)
            #pragma unroll
            for (int rg = 0; rg < 4; ++rg) {
                const float p = __expf(sacc[kf][rg] - mnew);
                sacc[kf][rg] = p;
                psum += p;
            }
        psum += __shfl_xor(psum, 16);
        psum += __shfl_xor(psum, 32);
        lrun = lrun * fac + psum;
        mrun = mnew;
        #pragma unroll
        for (int d = 0; d < 4; ++d) accO[d] *= fac;

        // ---- P^T -> bf16 via per-wave swizzled LDS (write 8B x4, read b128 x2)
        char* ptw = (char*)&PTs[w][0];
        #pragma unroll
        for (int kf = 0; kf < 4; ++kf) {
            u32x2 pk;
            pk[0] = pack2(sacc[kf][0], sacc[kf][1]);
            pk[1] = pack2(sacc[kf][2], sacc[kf][3]);
            *(u32x2*)(ptw + lq * 128 +
                      (((kf * 2 + (g >> 1)) ^ (lq & 7)) * 16) + (g & 1) * 8) = pk;
        }
        #pragma unroll
        for (int kh = 0; kh < 2; ++kh) {
            const s16x8 pb = *(const s16x8*)(ptw + lq * 128 +
                                             (((kh * 4 + g) ^ (lq & 7)) * 16));
            #pragma unroll
            for (int df = 0; df < 4; ++df) {
                const int row = df * 16 + lq;
                const s16x8 vf = *(const s16x8*)((const char*)VTs + row * 128 +
                                                 (((kh * 4 + g) ^ (row & 7)) * 16));
                accO[df] = __builtin_amdgcn_mfma_f32_16x16x32_bf16(vf, pb, accO[df], 0, 0, 0);
            }
        }
        __syncthreads();
    }

    const float inv = 1.0f / lrun;
    unsigned short* orow = sab + ((size_t)(b * S_ + i)) * D_ + hh * 64;
    #pragma unroll
    for (int df = 0; df < 4; ++df) {
        u32x2 pk;
        pk[0] = pack2(accO[df][0] * inv, accO[df][1] * inv);
        pk[1] = pack2(accO[df][2] * inv, accO[df][3] * inv);
        *(u32x2*)(orow + df * 16 + g * 4) = pk;
    }
}

// ---------------------------------------------------------------------------
__global__ __launch_bounds__(256) void embed_kernel(
    const int* __restrict__ x, const int* __restrict__ ign,
    const float* __restrict__ emb, const float* __restrict__ pos,
    float* __restrict__ h, unsigned short* __restrict__ hbf)
{
    const int row = blockIdx.x;
    const int s = row & (S_ - 1);
    const int tok = x[row];
    const float keep = (ign[row] == 0) ? 1.0f : 0.0f;
    const float* er = emb + (size_t)tok * D_;
    const float* pr = pos + (size_t)s * D_;
    float* hr = h + (size_t)row * D_;
    unsigned short* hb = hbf + (size_t)row * D_;
    for (int d = threadIdx.x; d < D_; d += 256) {
        const float t = er[d] + pr[d] * keep;
        hr[d] = t;
        hb[d] = f2bf(t);
    }
}

// ---------------------------------------------------------------------------
__global__ __launch_bounds__(256) void add_ln_kernel(
    const float* __restrict__ X, const float* __restrict__ Y,
    float* __restrict__ out, unsigned short* __restrict__ outbf)
{
    const int row = blockIdx.x;
    const int tid = threadIdx.x;
    __shared__ float buf[D_];
    __shared__ float red[256];
    const float* xr = X + (size_t)row * D_;
    const float* yr = Y + (size_t)row * D_;
    float s0 = 0.f;
    for (int d = tid; d < D_; d += 256) {
        const float t = xr[d] + yr[d];
        buf[d] = t;
        s0 += t;
    }
    red[tid] = s0; __syncthreads();
    for (int o = 128; o; o >>= 1) {
        if (tid < o) red[tid] += red[tid + o];
        __syncthreads();
    }
    const float mu = red[0] * (1.0f / D_);
    __syncthreads();
    float s1 = 0.f;
    for (int d = tid; d < D_; d += 256) {
        const float t = buf[d] - mu;
        s1 += t * t;
    }
    red[tid] = s1; __syncthreads();
    for (int o = 128; o; o >>= 1) {
        if (tid < o) red[tid] += red[tid + o];
        __syncthreads();
    }
    const float inv = 1.0f / sqrtf(red[0] * (1.0f / D_));
    float* orow = out + (size_t)row * D_;
    unsigned short* obf = outbf + (size_t)row * D_;
    for (int d = tid; d < D_; d += 256) {
        const float t = (buf[d] - mu) * inv;
        orow[d] = t;
        obf[d] = f2bf(t);
    }
}

// ---------------------------------------------------------------------------
extern "C" void kernel_launch(void* const* d_in, const int* in_sizes, int n_in,
                              void* d_out, int out_size, void* d_ws, size_t ws_size,
                              hipStream_t stream)
{
    const int*   x    = (const int*)d_in[0];
    const int*   ign  = (const int*)d_in[1];
    const float* emb  = (const float*)d_in[2];
    const float* pos  = (const float*)d_in[3];
    const float* Wq   = (const float*)d_in[4];
    const float* bq   = (const float*)d_in[5];
    const float* Wk   = (const float*)d_in[6];
    const float* bk   = (const float*)d_in[7];
    const float* Wv   = (const float*)d_in[8];
    const float* bv   = (const float*)d_in[9];
    const float* Wo   = (const float*)d_in[10];
    const float* bo   = (const float*)d_in[11];
    const float* W1   = (const float*)d_in[12];
    const float* b1   = (const float*)d_in[13];
    const float* W2   = (const float*)d_in[14];
    const float* b2   = (const float*)d_in[15];
    const float* Wout = (const float*)d_in[16];
    const float* bout = (const float*)d_in[17];
    float* outp = (float*)d_out;

    const size_t RC = (size_t)M_ * D_;            // 1572864
    const size_t F1 = (size_t)M_ * DH_;           // 6291456
    // fp32 {h,z,tmp} + bf16 {zbf,sabbf,qbf,kbf,vtb,f1bf} (+hbf)
    const size_t need_all = 3 * RC * 4 + (6 * RC + F1) * 2 + 4096;
    const bool big = ws_size >= need_all;

    float* fbase = big ? (float*)d_ws : (float*)d_out;  // d_out scratch is dead
    float* h   = fbase;                                 // before final GEMM writes it
    float* z   = h + RC;
    float* tmp = z + RC;
    unsigned short* ubase = (unsigned short*)(tmp + RC);
    unsigned short* zbf   = ubase;
    unsigned short* sabbf = zbf + RC;
    unsigned short* qbf   = sabbf + RC;
    unsigned short* kbf   = qbf + RC;
    unsigned short* vtb   = kbf + RC;   // [B][H][64][S] = RC elems
    unsigned short* f1bf  = vtb + RC;
    // hbf is live during the final GEMM (A operand) -> must not be in d_out
    unsigned short* hbf = big ? (f1bf + F1) : (unsigned short*)d_ws;

    embed_kernel<<<M_, 256, 0, stream>>>(x, ign, emb, pos, h, hbf);

    for (int l = 0; l < L_; ++l) {
        const float* Wql = Wq + (size_t)l * H_ * D_ * 64;
        const float* bql = bq + (size_t)l * H_ * 64;
        const float* Wkl = Wk + (size_t)l * H_ * D_ * 64;
        const float* bkl = bk + (size_t)l * H_ * 64;
        const float* Wvl = Wv + (size_t)l * H_ * D_ * 64;
        const float* bvl = bv + (size_t)l * H_ * 64;
        const float* Wol = Wo + (size_t)l * (H_ * 64) * D_;
        const float* bol = bo + (size_t)l * D_;
        const float* W1l = W1 + (size_t)l * D_ * DH_;
        const float* b1l = b1 + (size_t)l * DH_;
        const float* W2l = W2 + (size_t)l * DH_ * D_;
        const float* b2l = b2 + (size_t)l * D_;

        gemm_qkv3<<<dim3(6, 16, 3), 256, 0, stream>>>(
            hbf, Wql, Wkl, Wvl, bql, bkl, bvl, qbf, kbf, vtb, M_, 768, 768);

        fattn_kernel<<<dim3(S_ / 64, H_, B_), 256, 0, stream>>>(
            qbf, kbf, vtb, ign, sabbf);

        gemm_main<<<dim3(6, 16), 256, 0, stream>>>(
            sabbf, Wol, bol, tmp, M_, 768, 768, 0, 0);
        add_ln_kernel<<<M_, 256, 0, stream>>>(h, tmp, z, zbf);

        gemm_main<<<dim3(24, 16), 256, 0, stream>>>(
            zbf, W1l, b1l, f1bf, M_, 3072, 768, 2, 0);
        gemm_main<<<dim3(6, 16), 256, 0, stream>>>(
            f1bf, W2l, b2l, tmp, M_, 768, 3072, 1, 0);
        add_ln_kernel<<<M_, 256, 0, stream>>>(z, tmp, h, hbf);
    }

    gemm_main<<<dim3(V_ / 128, M_ / 128), 256, 0, stream>>>(
        hbf, Wout, bout, outp, M_, V_, 768, 0, 0);
}

// Round 4
// 658.548 us; speedup vs baseline: 5.7111x; 1.5567x over previous
//
#include <hip/hip_runtime.h>
#include <math.h>

static constexpr int L_ = 2, H_ = 12, D_ = 768, DH_ = 3072, V_ = 32000,
                     S_ = 1024, B_ = 2;
static constexpr int M_ = B_ * S_;  // 2048 token rows

typedef __attribute__((ext_vector_type(4))) float f32x4;
typedef __attribute__((ext_vector_type(8))) short s16x8;   // 8 bf16 = 4 VGPR
typedef __attribute__((ext_vector_type(2))) unsigned int u32x2;
typedef __attribute__((ext_vector_type(4))) unsigned int u32x4;

__device__ __forceinline__ unsigned short f2bf(float f) {
    unsigned u = __builtin_bit_cast(unsigned, f);
    u = (u + 0x7FFFu + ((u >> 16) & 1u)) >> 16;   // RTNE
    return (unsigned short)u;
}
__device__ __forceinline__ unsigned pack2(float a, float b) {
    return (unsigned)f2bf(a) | ((unsigned)f2bf(b) << 16);
}

__device__ __forceinline__ void gld16(const void* g, void* l) {
    __builtin_amdgcn_global_load_lds(
        (const __attribute__((address_space(1))) unsigned int*)g,
        (__attribute__((address_space(3))) unsigned int*)l, 16, 0, 0);
}

// ---------------------------------------------------------------------------
// Weight transpose: in [K][N] fp32 (mat z at z*K*N) -> out [N][K] bf16.
// grid (N/64, K/64, nmat), 256 threads, 64x64 tile via LDS.
// ---------------------------------------------------------------------------
__global__ __launch_bounds__(256) void wtr_kernel(
    const float* __restrict__ in, unsigned short* __restrict__ out, int K, int N)
{
    __shared__ unsigned short t[64 * 68];
    const size_t mo = (size_t)blockIdx.z * K * N;
    in  += mo; out += mo;
    const int n0 = blockIdx.x * 64, k0 = blockIdx.y * 64;
    const int tid = threadIdx.x;
    const int kr = tid >> 2, nc = (tid & 3) * 16;
    const float* src = in + (size_t)(k0 + kr) * N + n0 + nc;
    #pragma unroll
    for (int j = 0; j < 4; ++j) {
        const float4 v = *(const float4*)(src + j * 4);
        *(u32x2*)&t[kr * 68 + nc + j * 4] = (u32x2){pack2(v.x, v.y), pack2(v.z, v.w)};
    }
    __syncthreads();
    const int nr = tid >> 2, kc = (tid & 3) * 16;
    unsigned short v16[16];
    #pragma unroll
    for (int j = 0; j < 16; ++j) v16[j] = t[(kc + j) * 68 + nr];
    unsigned short* dst = out + (size_t)(n0 + nr) * K + k0 + kc;
    ((u32x4*)dst)[0] = *(u32x4*)&v16[0];
    ((u32x4*)dst)[1] = *(u32x4*)&v16[8];
}

// ---------------------------------------------------------------------------
// bf16 MFMA GEMM, both operands via global_load_lds (swizzled source):
// C[M,N] = A[M,K](bf16) @ BT[N,K](bf16)^T + bias
// act 0: f32 out. 1: f32+exact GELU. 2: bf16 out [M][N]. 3: bf16 V^T [B][H][64][S].
// tile 128x128, BK=64, 256 threads (4 waves 2x2), mfma_f32_16x16x32_bf16.
// ---------------------------------------------------------------------------
__device__ __forceinline__ void gemm_bt_body(
    const unsigned short* __restrict__ A, const unsigned short* __restrict__ BT,
    const float* __restrict__ bias, void* __restrict__ Cp,
    int N, int K, int act, int bx, int by)
{
    __shared__ unsigned short As[8192];   // [row 128][k 64], swizzled granules
    __shared__ unsigned short Bs[8192];   // [col 128][k 64], swizzled granules
    const int tid = threadIdx.x;
    const int l   = tid & 63, wid = tid >> 6;
    const int wr  = wid >> 1, wc = wid & 1;
    const int brow = by * 128, bn = bx * 128;

    f32x4 acc[4][4];
    #pragma unroll
    for (int i = 0; i < 4; ++i)
        #pragma unroll
        for (int j = 0; j < 4; ++j) acc[i][j] = (f32x4)0.f;

    const int arow = tid >> 3;                      // 0..31 per round
    const int aq   = (tid & 7) ^ (arow & 7);        // inverse-swizzled source granule
    const unsigned short* Abase = A  + (size_t)(brow + arow) * K + aq * 8;
    const unsigned short* Bbase = BT + (size_t)(bn   + arow) * K + aq * 8;

    for (int k0 = 0; k0 < K; k0 += 64) {
        #pragma unroll
        for (int r = 0; r < 4; ++r)
            gld16(Abase + (size_t)r * 32 * K + k0, (char*)As + r * 4096 + wid * 1024);
        #pragma unroll
        for (int r = 0; r < 4; ++r)
            gld16(Bbase + (size_t)r * 32 * K + k0, (char*)Bs + r * 4096 + wid * 1024);
        __syncthreads();

        #pragma unroll
        for (int kk = 0; kk < 2; ++kk) {
            s16x8 af[4], bf[4];
            #pragma unroll
            for (int mf = 0; mf < 4; ++mf) {
                const int row = wr * 64 + mf * 16 + (l & 15);
                const int gg  = (kk * 4 + (l >> 4)) ^ (row & 7);
                af[mf] = *(const s16x8*)((const char*)As + row * 128 + gg * 16);
            }
            #pragma unroll
            for (int nf = 0; nf < 4; ++nf) {
                const int col = wc * 64 + nf * 16 + (l & 15);
                const int gg  = (kk * 4 + (l >> 4)) ^ (col & 7);
                bf[nf] = *(const s16x8*)((const char*)Bs + col * 128 + gg * 16);
            }
            #pragma unroll
            for (int mf = 0; mf < 4; ++mf)
                #pragma unroll
                for (int nf = 0; nf < 4; ++nf)
                    acc[mf][nf] = __builtin_amdgcn_mfma_f32_16x16x32_bf16(
                        af[mf], bf[nf], acc[mf][nf], 0, 0, 0);
        }
        __syncthreads();
    }

    const int lr = l >> 4, lc = l & 15;
    #pragma unroll
    for (int nf = 0; nf < 4; ++nf) {
        const int gcol = bn + wc * 64 + nf * 16 + lc;
        const float bb = bias[gcol];
        #pragma unroll
        for (int mf = 0; mf < 4; ++mf) {
            if (act == 3) {
                const int grow0 = brow + wr * 64 + mf * 16 + lr * 4;
                const int b = grow0 >> 10, s0 = grow0 & (S_ - 1);
                const int head = gcol >> 6, d = gcol & 63;
                u32x2 pk;
                pk[0] = pack2(acc[mf][nf][0] + bb, acc[mf][nf][1] + bb);
                pk[1] = pack2(acc[mf][nf][2] + bb, acc[mf][nf][3] + bb);
                unsigned short* dst = (unsigned short*)Cp +
                    (((size_t)b * H_ + head) * 64 + d) * S_ + s0;
                *(u32x2*)dst = pk;
            } else {
                #pragma unroll
                for (int rg = 0; rg < 4; ++rg) {
                    const int grow = brow + wr * 64 + mf * 16 + lr * 4 + rg;
                    float vv = acc[mf][nf][rg] + bb;
                    if (act == 1) vv = 0.5f * vv * (1.0f + erff(vv * 0.70710678118654752f));
                    if (act == 2)
                        ((unsigned short*)Cp)[(size_t)grow * N + gcol] = f2bf(vv);
                    else
                        ((float*)Cp)[(size_t)grow * N + gcol] = vv;
                }
            }
        }
    }
}

// XCD-aware bijective swizzle (nwg always a multiple of 8 here): each XCD gets
// a contiguous virtual range; decode bx = s/gy so same-XCD blocks share B panels.
__device__ __forceinline__ void xcd_decode(int& bx, int& by) {
    const int gx = gridDim.x, gy = gridDim.y;
    const int nwg = gx * gy;
    const int flat = blockIdx.y * gx + blockIdx.x;
    const int s = (flat & 7) * (nwg >> 3) + (flat >> 3);
    bx = s / gy;
    by = s % gy;
}

__global__ __launch_bounds__(256) void gemm_bt(
    const unsigned short* __restrict__ A, const unsigned short* __restrict__ BT,
    const float* __restrict__ bias, void* __restrict__ C, int N, int K, int act)
{
    int bx, by; xcd_decode(bx, by);
    gemm_bt_body(A, BT, bias, C, N, K, act, bx, by);
}

__global__ __launch_bounds__(256) void gemm_qkv3(
    const unsigned short* __restrict__ A,
    const unsigned short* __restrict__ qT, const unsigned short* __restrict__ kT,
    const unsigned short* __restrict__ vT,
    const float* __restrict__ bq, const float* __restrict__ bk, const float* __restrict__ bv,
    unsigned short* __restrict__ q, unsigned short* __restrict__ k,
    unsigned short* __restrict__ v)
{
    const unsigned short* BT; const float* bi; unsigned short* C; int act;
    if (blockIdx.z == 0)      { BT = qT; bi = bq; C = q; act = 2; }
    else if (blockIdx.z == 1) { BT = kT; bi = bk; C = k; act = 2; }
    else                      { BT = vT; bi = bv; C = v; act = 3; }
    int bx, by; xcd_decode(bx, by);
    gemm_bt_body(A, BT, bi, C, 768, 768, act, bx, by);
}

// ---------------------------------------------------------------------------
// Fallback GEMM (fp32 B in [K][N], in-kernel convert) — only used when ws is
// too small to hold the transposed bf16 Wout. act 0 only.
// ---------------------------------------------------------------------------
__global__ __launch_bounds__(256) void gemm_f32b(
    const unsigned short* __restrict__ A, const float* __restrict__ B,
    const float* __restrict__ bias, float* __restrict__ C, int N, int K)
{
    __shared__ unsigned short As[8192];
    __shared__ unsigned short Bs[8192];
    const int tid = threadIdx.x;
    const int l   = tid & 63, wid = tid >> 6;
    const int wr  = wid >> 1, wc = wid & 1;
    const int brow = blockIdx.y * 128, bn = blockIdx.x * 128;
    f32x4 acc[4][4];
    #pragma unroll
    for (int i = 0; i < 4; ++i)
        #pragma unroll
        for (int j = 0; j < 4; ++j) acc[i][j] = (f32x4)0.f;
    const int arow = tid >> 3;
    const int aq   = (tid & 7) ^ (arow & 7);
    const int bkq  = tid >> 5, bnq = tid & 31;
    for (int k0 = 0; k0 < K; k0 += 64) {
        #pragma unroll
        for (int r = 0; r < 4; ++r)
            gld16(A + (size_t)(brow + r * 32 + arow) * K + k0 + aq * 8,
                  (char*)As + r * 4096 + wid * 1024);
        #pragma unroll
        for (int r = 0; r < 2; ++r) {
            const int kb = r * 32 + bkq * 4;
            const float* p = B + (size_t)(k0 + kb) * N + bn + bnq * 4;
            const float4 v0 = *(const float4*)(p);
            const float4 v1 = *(const float4*)(p + N);
            const float4 v2 = *(const float4*)(p + 2 * (size_t)N);
            const float4 v3 = *(const float4*)(p + 3 * (size_t)N);
            const int g = kb >> 3, bytek = (kb & 4) * 2;
            const float* f0 = (const float*)&v0; const float* f1 = (const float*)&v1;
            const float* f2 = (const float*)&v2; const float* f3 = (const float*)&v3;
            #pragma unroll
            for (int i = 0; i < 4; ++i) {
                const int n = bnq * 4 + i;
                char* dst = (char*)Bs + n * 128 + ((g ^ (n & 7)) * 16) + bytek;
                *(u32x2*)dst = (u32x2){pack2(f0[i], f1[i]), pack2(f2[i], f3[i])};
            }
        }
        __syncthreads();
        #pragma unroll
        for (int kk = 0; kk < 2; ++kk) {
            s16x8 af[4], bf[4];
            #pragma unroll
            for (int mf = 0; mf < 4; ++mf) {
                const int row = wr * 64 + mf * 16 + (l & 15);
                const int gg  = (kk * 4 + (l >> 4)) ^ (row & 7);
                af[mf] = *(const s16x8*)((const char*)As + row * 128 + gg * 16);
            }
            #pragma unroll
            for (int nf = 0; nf < 4; ++nf) {
                const int col = wc * 64 + nf * 16 + (l & 15);
                const int gg  = (kk * 4 + (l >> 4)) ^ (col & 7);
                bf[nf] = *(const s16x8*)((const char*)Bs + col * 128 + gg * 16);
            }
            #pragma unroll
            for (int mf = 0; mf < 4; ++mf)
                #pragma unroll
                for (int nf = 0; nf < 4; ++nf)
                    acc[mf][nf] = __builtin_amdgcn_mfma_f32_16x16x32_bf16(
                        af[mf], bf[nf], acc[mf][nf], 0, 0, 0);
        }
        __syncthreads();
    }
    const int lr = l >> 4, lc = l & 15;
    #pragma unroll
    for (int nf = 0; nf < 4; ++nf) {
        const int gcol = bn + wc * 64 + nf * 16 + lc;
        const float bb = bias[gcol];
        #pragma unroll
        for (int mf = 0; mf < 4; ++mf)
            #pragma unroll
            for (int rg = 0; rg < 4; ++rg) {
                const int grow = brow + wr * 64 + mf * 16 + lr * 4 + rg;
                C[(size_t)grow * N + gcol] = acc[mf][nf][rg] + bb;
            }
    }
}

// ---------------------------------------------------------------------------
// Flash attention (unchanged from round 3). q,k: bf16 [M][768]; vt: [B][H][64][S].
// ---------------------------------------------------------------------------
__global__ __launch_bounds__(256) void fattn_kernel(
    const unsigned short* __restrict__ qm, const unsigned short* __restrict__ km,
    const unsigned short* __restrict__ vt, const int* __restrict__ ign,
    unsigned short* __restrict__ sab)
{
    __shared__ unsigned short Ks[4096];
    __shared__ unsigned short VTs[4096];
    __shared__ int igns[64];
    __shared__ unsigned short PTs[4][1024];

    const int qt = blockIdx.x, hh = blockIdx.y, b = blockIdx.z;
    const int tid = threadIdx.x;
    const int l = tid & 63, w = tid >> 6;
    const int g = l >> 4, lq = l & 15;
    const int i = qt * 64 + w * 16 + lq;

    const size_t qgb = ((size_t)(b * S_ + i)) * D_ + hh * 64;
    const s16x8 qf0 = *(const s16x8*)(qm + qgb + g * 8);
    const s16x8 qf1 = *(const s16x8*)(qm + qgb + 32 + g * 8);

    f32x4 accO[4];
    #pragma unroll
    for (int d = 0; d < 4; ++d) accO[d] = (f32x4)0.f;
    float mrun = -1e30f, lrun = 0.f;

    const int srow = tid >> 3, sg = tid & 7;

    for (int t = 0; t <= qt; ++t) {
        const int j0 = t * 64;
        #pragma unroll
        for (int r = 0; r < 2; ++r) {
            const int row = r * 32 + srow;
            const int gsw = (sg ^ (row & 7)) * 8;
            gld16(km + (size_t)(b * S_ + j0 + row) * D_ + hh * 64 + gsw,
                  (char*)Ks + (r * 256 + tid) * 16);
            gld16(vt + ((size_t)(b * H_ + hh) * 64 + row) * S_ + j0 + gsw,
                  (char*)VTs + (r * 256 + tid) * 16);
        }
        if (tid < 64) igns[tid] = ign[b * S_ + j0 + tid];
        __syncthreads();

        f32x4 sacc[4];
        #pragma unroll
        for (int kf = 0; kf < 4; ++kf) sacc[kf] = (f32x4)0.f;
        #pragma unroll
        for (int kk = 0; kk < 2; ++kk) {
            const s16x8 qv = kk ? qf1 : qf0;
            #pragma unroll
            for (int kf = 0; kf < 4; ++kf) {
                const int row = kf * 16 + lq;
                const s16x8 kv = *(const s16x8*)((const char*)Ks + row * 128 +
                                                 (((kk * 4 + g) ^ (row & 7)) * 16));
                sacc[kf] = __builtin_amdgcn_mfma_f32_16x16x32_bf16(kv, qv, sacc[kf], 0, 0, 0);
            }
        }

        float tmax = -INFINITY;
        #pragma unroll
        for (int kf = 0; kf < 4; ++kf)
            #pragma unroll
            for (int rg = 0; rg < 4; ++rg) {
                const int j = j0 + kf * 16 + g * 4 + rg;
                float s = sacc[kf][rg] * 0.125f;
                const bool ok = (j <= i) && (igns[kf * 16 + g * 4 + rg] == 0 || j == i);
                s = ok ? s : -INFINITY;
                sacc[kf][rg] = s;
                tmax = fmaxf(tmax, s);
            }
        tmax = fmaxf(tmax, __shfl_xor(tmax, 16));
        tmax = fmaxf(tmax, __shfl_xor(tmax, 32));
        const float mnew = fmaxf(mrun, tmax);
        const float fac = __expf(mrun - mnew);
        float psum = 0.f;
        #pragma unroll
        for (int kf = 0; kf < 4; ++kf)
            #pragma unroll
            for (int rg = 0; rg < 4; ++rg) {
                const float p = __expf(sacc[kf][rg] - mnew);
                sacc[kf][rg] = p;
                psum += p;
            }
        psum += __shfl_xor(psum, 16);
        psum += __shfl_xor(psum, 32);
        lrun = lrun * fac + psum;
        mrun = mnew;
        #pragma unroll
        for (int d = 0; d < 4; ++d) accO[d] *= fac;

        char* ptw = (char*)&PTs[w][0];
        #pragma unroll
        for (int kf = 0; kf < 4; ++kf) {
            u32x2 pk;
            pk[0] = pack2(sacc[kf][0], sacc[kf][1]);
            pk[1] = pack2(sacc[kf][2], sacc[kf][3]);
            *(u32x2*)(ptw + lq * 128 +
                      (((kf * 2 + (g >> 1)) ^ (lq & 7)) * 16) + (g & 1) * 8) = pk;
        }
        #pragma unroll
        for (int kh = 0; kh < 2; ++kh) {
            const s16x8 pb = *(const s16x8*)(ptw + lq * 128 +
                                             (((kh * 4 + g) ^ (lq & 7)) * 16));
            #pragma unroll
            for (int df = 0; df < 4; ++df) {
                const int row = df * 16 + lq;
                const s16x8 vf = *(const s16x8*)((const char*)VTs + row * 128 +
                                                 (((kh * 4 + g) ^ (row & 7)) * 16));
                accO[df] = __builtin_amdgcn_mfma_f32_16x16x32_bf16(vf, pb, accO[df], 0, 0, 0);
            }
        }
        __syncthreads();
    }

    const float inv = 1.0f / lrun;
    unsigned short* orow = sab + ((size_t)(b * S_ + i)) * D_ + hh * 64;
    #pragma unroll
    for (int df = 0; df < 4; ++df) {
        u32x2 pk;
        pk[0] = pack2(accO[df][0] * inv, accO[df][1] * inv);
        pk[1] = pack2(accO[df][2] * inv, accO[df][3] * inv);
        *(u32x2*)(orow + df * 16 + g * 4) = pk;
    }
}

// ---------------------------------------------------------------------------
__global__ __launch_bounds__(256) void embed_kernel(
    const int* __restrict__ x, const int* __restrict__ ign,
    const float* __restrict__ emb, const float* __restrict__ pos,
    float* __restrict__ h, unsigned short* __restrict__ hbf)
{
    const int row = blockIdx.x;
    const int s = row & (S_ - 1);
    const int tok = x[row];
    const float keep = (ign[row] == 0) ? 1.0f : 0.0f;
    const float* er = emb + (size_t)tok * D_;
    const float* pr = pos + (size_t)s * D_;
    float* hr = h + (size_t)row * D_;
    unsigned short* hb = hbf + (size_t)row * D_;
    for (int d = threadIdx.x; d < D_; d += 256) {
        const float t = er[d] + pr[d] * keep;
        hr[d] = t;
        hb[d] = f2bf(t);
    }
}

// ---------------------------------------------------------------------------
__global__ __launch_bounds__(256) void add_ln_kernel(
    const float* __restrict__ X, const float* __restrict__ Y,
    float* __restrict__ out, unsigned short* __restrict__ outbf)
{
    const int row = blockIdx.x;
    const int tid = threadIdx.x;
    __shared__ float buf[D_];
    __shared__ float red[256];
    const float* xr = X + (size_t)row * D_;
    const float* yr = Y + (size_t)row * D_;
    float s0 = 0.f;
    for (int d = tid; d < D_; d += 256) {
        const float t = xr[d] + yr[d];
        buf[d] = t;
        s0 += t;
    }
    red[tid] = s0; __syncthreads();
    for (int o = 128; o; o >>= 1) {
        if (tid < o) red[tid] += red[tid + o];
        __syncthreads();
    }
    const float mu = red[0] * (1.0f / D_);
    __syncthreads();
    float s1 = 0.f;
    for (int d = tid; d < D_; d += 256) {
        const float t = buf[d] - mu;
        s1 += t * t;
    }
    red[tid] = s1; __syncthreads();
    for (int o = 128; o; o >>= 1) {
        if (tid < o) red[tid] += red[tid + o];
        __syncthreads();
    }
    const float inv = 1.0f / sqrtf(red[0] * (1.0f / D_));
    float* orow = out + (size_t)row * D_;
    unsigned short* obf = outbf + (size_t)row * D_;
    for (int d = tid; d < D_; d += 256) {
        const float t = (buf[d] - mu) * inv;
        orow[d] = t;
        obf[d] = f2bf(t);
    }
}

// ---------------------------------------------------------------------------
extern "C" void kernel_launch(void* const* d_in, const int* in_sizes, int n_in,
                              void* d_out, int out_size, void* d_ws, size_t ws_size,
                              hipStream_t stream)
{
    const int*   x    = (const int*)d_in[0];
    const int*   ign  = (const int*)d_in[1];
    const float* emb  = (const float*)d_in[2];
    const float* pos  = (const float*)d_in[3];
    const float* Wq   = (const float*)d_in[4];
    const float* bq   = (const float*)d_in[5];
    const float* Wk   = (const float*)d_in[6];
    const float* bk   = (const float*)d_in[7];
    const float* Wv   = (const float*)d_in[8];
    const float* bv   = (const float*)d_in[9];
    const float* Wo   = (const float*)d_in[10];
    const float* bo   = (const float*)d_in[11];
    const float* W1   = (const float*)d_in[12];
    const float* b1   = (const float*)d_in[13];
    const float* W2   = (const float*)d_in[14];
    const float* b2   = (const float*)d_in[15];
    const float* Wout = (const float*)d_in[16];
    const float* bout = (const float*)d_in[17];
    float* outp = (float*)d_out;

    const size_t RC = (size_t)M_ * D_;        // 1572864
    const size_t F1 = (size_t)M_ * DH_;       // 6291456
    const size_t WH = (size_t)H_ * 64 * D_;   // 589824 (one QKV/Wo matrix)
    const size_t WF = (size_t)D_ * DH_;       // 2359296 (one W1/W2 matrix)
    const size_t WOUTE = (size_t)V_ * D_;     // 24576000

    // Tiered arena allocator. d_out (262 MB) is dead scratch until the final
    // GEMM; hbf and woutT are live DURING the final GEMM -> ws only.
    char* wsp = (char*)d_ws;
    size_t wsleft = ws_size;
    char* dop = (char*)d_out;
    auto alloc = [&](size_t bytes, bool must_ws) -> void* {
        bytes = (bytes + 255) & ~(size_t)255;
        if (wsleft >= bytes) { void* p = wsp; wsp += bytes; wsleft -= bytes; return p; }
        if (must_ws) return nullptr;
        void* p = dop; dop += bytes; return p;
    };

    unsigned short* hbf   = (unsigned short*)alloc(RC * 2, true);
    unsigned short* woutT = (unsigned short*)alloc(WOUTE * 2, true);
    float* h   = (float*)alloc(RC * 4, false);
    float* z   = (float*)alloc(RC * 4, false);
    float* tmp = (float*)alloc(RC * 4, false);
    unsigned short* zbf   = (unsigned short*)alloc(RC * 2, false);
    unsigned short* sabbf = (unsigned short*)alloc(RC * 2, false);
    unsigned short* qbf   = (unsigned short*)alloc(RC * 2, false);
    unsigned short* kbf   = (unsigned short*)alloc(RC * 2, false);
    unsigned short* vtb   = (unsigned short*)alloc(RC * 2, false);
    unsigned short* f1bf  = (unsigned short*)alloc(F1 * 2, false);
    unsigned short* wqT = (unsigned short*)alloc(L_ * WH * 2, false);
    unsigned short* wkT = (unsigned short*)alloc(L_ * WH * 2, false);
    unsigned short* wvT = (unsigned short*)alloc(L_ * WH * 2, false);
    unsigned short* woT = (unsigned short*)alloc(L_ * WH * 2, false);
    unsigned short* w1T = (unsigned short*)alloc(L_ * WF * 2, false);
    unsigned short* w2T = (unsigned short*)alloc(L_ * WF * 2, false);

    embed_kernel<<<M_, 256, 0, stream>>>(x, ign, emb, pos, h, hbf);

    // One-time weight transposes: [K][N] fp32 -> [N][K] bf16
    for (int l = 0; l < L_; ++l) {
        wtr_kernel<<<dim3(1, 12, H_), 256, 0, stream>>>(Wq + l * WH, wqT + l * WH, D_, 64);
        wtr_kernel<<<dim3(1, 12, H_), 256, 0, stream>>>(Wk + l * WH, wkT + l * WH, D_, 64);
        wtr_kernel<<<dim3(1, 12, H_), 256, 0, stream>>>(Wv + l * WH, wvT + l * WH, D_, 64);
        wtr_kernel<<<dim3(12, 12, 1), 256, 0, stream>>>(Wo + l * WH, woT + l * WH, D_, D_);
        wtr_kernel<<<dim3(48, 12, 1), 256, 0, stream>>>(W1 + l * WF, w1T + l * WF, D_, DH_);
        wtr_kernel<<<dim3(12, 48, 1), 256, 0, stream>>>(W2 + l * WF, w2T + l * WF, DH_, D_);
    }
    if (woutT)
        wtr_kernel<<<dim3(V_ / 64, 12, 1), 256, 0, stream>>>(Wout, woutT, D_, V_);

    for (int l = 0; l < L_; ++l) {
        gemm_qkv3<<<dim3(6, 16, 3), 256, 0, stream>>>(
            hbf, wqT + l * WH, wkT + l * WH, wvT + l * WH,
            bq + l * 768, bk + l * 768, bv + l * 768, qbf, kbf, vtb);

        fattn_kernel<<<dim3(S_ / 64, H_, B_), 256, 0, stream>>>(
            qbf, kbf, vtb, ign, sabbf);

        gemm_bt<<<dim3(6, 16), 256, 0, stream>>>(
            sabbf, woT + l * WH, bo + l * D_, tmp, D_, D_, 0);
        add_ln_kernel<<<M_, 256, 0, stream>>>(h, tmp, z, zbf);

        gemm_bt<<<dim3(24, 16), 256, 0, stream>>>(
            zbf, w1T + l * WF, b1 + l * DH_, f1bf, DH_, D_, 2);
        gemm_bt<<<dim3(6, 16), 256, 0, stream>>>(
            f1bf, w2T + l * WF, b2 + l * D_, tmp, D_, DH_, 1);
        add_ln_kernel<<<M_, 256, 0, stream>>>(z, tmp, h, hbf);
    }

    if (woutT)
        gemm_bt<<<dim3(V_ / 128, M_ / 128), 256, 0, stream>>>(
            hbf, woutT, bout, outp, V_, D_, 0);
    else
        gemm_f32b<<<dim3(V_ / 128, M_ / 128), 256, 0, stream>>>(
            hbf, Wout, bout, outp, V_, D_);
}

// Round 5
// 647.709 us; speedup vs baseline: 5.8066x; 1.0167x over previous
//
#include <hip/hip_runtime.h>
#include <math.h>

static constexpr int L_ = 2, H_ = 12, D_ = 768, DH_ = 3072, V_ = 32000,
                     S_ = 1024, B_ = 2;
static constexpr int M_ = B_ * S_;  // 2048 token rows

typedef __attribute__((ext_vector_type(4))) float f32x4;
typedef __attribute__((ext_vector_type(8))) short s16x8;   // 8 bf16 = 4 VGPR
typedef __attribute__((ext_vector_type(2))) unsigned int u32x2;
typedef __attribute__((ext_vector_type(4))) unsigned int u32x4;

__device__ __forceinline__ unsigned short f2bf(float f) {
    unsigned u = __builtin_bit_cast(unsigned, f);
    u = (u + 0x7FFFu + ((u >> 16) & 1u)) >> 16;   // RTNE
    return (unsigned short)u;
}
__device__ __forceinline__ unsigned pack2(float a, float b) {
    return (unsigned)f2bf(a) | ((unsigned)f2bf(b) << 16);
}

__device__ __forceinline__ void gld16(const void* g, void* l) {
    __builtin_amdgcn_global_load_lds(
        (const __attribute__((address_space(1))) unsigned int*)g,
        (__attribute__((address_space(3))) unsigned int*)l, 16, 0, 0);
}

// ---------------------------------------------------------------------------
// Weight transpose: in [K][N] fp32 (mat z at z*K*N) -> out [N][K] bf16.
// ---------------------------------------------------------------------------
__global__ __launch_bounds__(256) void wtr_kernel(
    const float* __restrict__ in, unsigned short* __restrict__ out, int K, int N)
{
    __shared__ unsigned short t[64 * 68];
    const size_t mo = (size_t)blockIdx.z * K * N;
    in  += mo; out += mo;
    const int n0 = blockIdx.x * 64, k0 = blockIdx.y * 64;
    const int tid = threadIdx.x;
    const int kr = tid >> 2, nc = (tid & 3) * 16;
    const float* src = in + (size_t)(k0 + kr) * N + n0 + nc;
    #pragma unroll
    for (int j = 0; j < 4; ++j) {
        const float4 v = *(const float4*)(src + j * 4);
        *(u32x2*)&t[kr * 68 + nc + j * 4] = (u32x2){pack2(v.x, v.y), pack2(v.z, v.w)};
    }
    __syncthreads();
    const int nr = tid >> 2, kc = (tid & 3) * 16;
    unsigned short v16[16];
    #pragma unroll
    for (int j = 0; j < 16; ++j) v16[j] = t[(kc + j) * 68 + nr];
    unsigned short* dst = out + (size_t)(n0 + nr) * K + k0 + kc;
    ((u32x4*)dst)[0] = *(u32x4*)&v16[0];
    ((u32x4*)dst)[1] = *(u32x4*)&v16[8];
}

// ---------------------------------------------------------------------------
// 128x128 m97-structure GEMM (unchanged): used for all mid-size GEMMs.
// ---------------------------------------------------------------------------
__device__ __forceinline__ void gemm_bt_body(
    const unsigned short* __restrict__ A, const unsigned short* __restrict__ BT,
    const float* __restrict__ bias, void* __restrict__ Cp,
    int N, int K, int act, int bx, int by)
{
    __shared__ unsigned short As[8192];
    __shared__ unsigned short Bs[8192];
    const int tid = threadIdx.x;
    const int l   = tid & 63, wid = tid >> 6;
    const int wr  = wid >> 1, wc = wid & 1;
    const int brow = by * 128, bn = bx * 128;

    f32x4 acc[4][4];
    #pragma unroll
    for (int i = 0; i < 4; ++i)
        #pragma unroll
        for (int j = 0; j < 4; ++j) acc[i][j] = (f32x4)0.f;

    const int arow = tid >> 3;
    const int aq   = (tid & 7) ^ (arow & 7);
    const unsigned short* Abase = A  + (size_t)(brow + arow) * K + aq * 8;
    const unsigned short* Bbase = BT + (size_t)(bn   + arow) * K + aq * 8;

    for (int k0 = 0; k0 < K; k0 += 64) {
        #pragma unroll
        for (int r = 0; r < 4; ++r)
            gld16(Abase + (size_t)r * 32 * K + k0, (char*)As + r * 4096 + wid * 1024);
        #pragma unroll
        for (int r = 0; r < 4; ++r)
            gld16(Bbase + (size_t)r * 32 * K + k0, (char*)Bs + r * 4096 + wid * 1024);
        __syncthreads();

        #pragma unroll
        for (int kk = 0; kk < 2; ++kk) {
            s16x8 af[4], bf[4];
            #pragma unroll
            for (int mf = 0; mf < 4; ++mf) {
                const int row = wr * 64 + mf * 16 + (l & 15);
                const int gg  = (kk * 4 + (l >> 4)) ^ (row & 7);
                af[mf] = *(const s16x8*)((const char*)As + row * 128 + gg * 16);
            }
            #pragma unroll
            for (int nf = 0; nf < 4; ++nf) {
                const int col = wc * 64 + nf * 16 + (l & 15);
                const int gg  = (kk * 4 + (l >> 4)) ^ (col & 7);
                bf[nf] = *(const s16x8*)((const char*)Bs + col * 128 + gg * 16);
            }
            #pragma unroll
            for (int mf = 0; mf < 4; ++mf)
                #pragma unroll
                for (int nf = 0; nf < 4; ++nf)
                    acc[mf][nf] = __builtin_amdgcn_mfma_f32_16x16x32_bf16(
                        af[mf], bf[nf], acc[mf][nf], 0, 0, 0);
        }
        __syncthreads();
    }

    const int lr = l >> 4, lc = l & 15;
    #pragma unroll
    for (int nf = 0; nf < 4; ++nf) {
        const int gcol = bn + wc * 64 + nf * 16 + lc;
        const float bb = bias[gcol];
        #pragma unroll
        for (int mf = 0; mf < 4; ++mf) {
            if (act == 3) {
                const int grow0 = brow + wr * 64 + mf * 16 + lr * 4;
                const int b = grow0 >> 10, s0 = grow0 & (S_ - 1);
                const int head = gcol >> 6, d = gcol & 63;
                u32x2 pk;
                pk[0] = pack2(acc[mf][nf][0] + bb, acc[mf][nf][1] + bb);
                pk[1] = pack2(acc[mf][nf][2] + bb, acc[mf][nf][3] + bb);
                unsigned short* dst = (unsigned short*)Cp +
                    (((size_t)b * H_ + head) * 64 + d) * S_ + s0;
                *(u32x2*)dst = pk;
            } else {
                #pragma unroll
                for (int rg = 0; rg < 4; ++rg) {
                    const int grow = brow + wr * 64 + mf * 16 + lr * 4 + rg;
                    float vv = acc[mf][nf][rg] + bb;
                    if (act == 1) vv = 0.5f * vv * (1.0f + erff(vv * 0.70710678118654752f));
                    if (act == 2)
                        ((unsigned short*)Cp)[(size_t)grow * N + gcol] = f2bf(vv);
                    else
                        ((float*)Cp)[(size_t)grow * N + gcol] = vv;
                }
            }
        }
    }
}

__device__ __forceinline__ void xcd_decode(int& bx, int& by) {
    const int gx = gridDim.x, gy = gridDim.y;
    const int nwg = gx * gy;
    const int flat = blockIdx.y * gx + blockIdx.x;
    const int s = (flat & 7) * (nwg >> 3) + (flat >> 3);
    bx = s / gy;
    by = s % gy;
}

__global__ __launch_bounds__(256) void gemm_bt(
    const unsigned short* __restrict__ A, const unsigned short* __restrict__ BT,
    const float* __restrict__ bias, void* __restrict__ C, int N, int K, int act)
{
    int bx, by; xcd_decode(bx, by);
    gemm_bt_body(A, BT, bias, C, N, K, act, bx, by);
}

__global__ __launch_bounds__(256) void gemm_qkv3(
    const unsigned short* __restrict__ A,
    const unsigned short* __restrict__ qT, const unsigned short* __restrict__ kT,
    const unsigned short* __restrict__ vT,
    const float* __restrict__ bq, const float* __restrict__ bk, const float* __restrict__ bv,
    unsigned short* __restrict__ q, unsigned short* __restrict__ k,
    unsigned short* __restrict__ v)
{
    const unsigned short* BT; const float* bi; unsigned short* C; int act;
    if (blockIdx.z == 0)      { BT = qT; bi = bq; C = q; act = 2; }
    else if (blockIdx.z == 1) { BT = kT; bi = bk; C = k; act = 2; }
    else                      { BT = vT; bi = bv; C = v; act = 3; }
    int bx, by; xcd_decode(bx, by);
    gemm_bt_body(A, BT, bi, C, 768, 768, act, bx, by);
}

// ---------------------------------------------------------------------------
// 256x256 8-wave deep-pipelined GEMM (T2+T3+T4+T5), f32 out + bias.
// BK=32, 4 LDS K-tile slots (128 KiB), 3-tile prefetch, counted vmcnt(8),
// 2 phases/tile: {ds_read ∥ 2 gld16 -> s_barrier -> setprio(1) + 16 MFMA}.
// Per-wave output 128x64 (wave grid 2Mx4N). Granule XOR-swizzle (2-way max).
// ---------------------------------------------------------------------------
__global__ __launch_bounds__(512) void gemm_bt256(
    const unsigned short* __restrict__ A, const unsigned short* __restrict__ BT,
    const float* __restrict__ bias, float* __restrict__ C, int N, int K)
{
    __shared__ char lds[131072];   // A slots [4][16384] @0, B slots @65536
    const int tid = threadIdx.x;
    const int l = tid & 63, wid = tid >> 6;
    const int wr = wid >> 2, wc = wid & 3;
    const int lq = l & 15, lg = l >> 4;

    int bx, by;
    {
        const int gx = gridDim.x, gy = gridDim.y;
        const int nwg = gx * gy;
        const int flat = blockIdx.y * gx + blockIdx.x;
        const int s = (flat & 7) * (nwg >> 3) + (flat >> 3);
        bx = s / gy; by = s % gy;
    }
    const int brow = by * 256, bn = bx * 256;
    const int NT = K >> 5;

    // staging geometry: round q covers rows q*128..q*128+127, pos p = tid&3
    const int r0 = tid >> 2;                       // 0..127
    const int p  = tid & 3;
    const int sw0 = (r0 ^ (r0 >> 2)) & 3;          // same for r0+128
    const int g0 = p ^ sw0;                        // source k-granule
    const size_t soff0 = (size_t)r0 * K + g0 * 8;
    const size_t soff1 = (size_t)(r0 + 128) * K + g0 * 8;
    const unsigned short* Agb = A  + (size_t)brow * K;
    const unsigned short* Bgb = BT + (size_t)bn * K;

    f32x4 acc[8][4];
    #pragma unroll
    for (int i = 0; i < 8; ++i)
        #pragma unroll
        for (int j = 0; j < 4; ++j) acc[i][j] = (f32x4)0.f;

    // prologue: stage tiles 0..2 into slots 0..2 (12 gld16/thread)
    for (int t = 0; t < 3; ++t) {
        const int k0 = t << 5;
        char* da = lds + t * 16384 + wid * 1024;
        char* db = lds + 65536 + t * 16384 + wid * 1024;
        gld16(Agb + soff0 + k0, da);
        gld16(Agb + soff1 + k0, da + 8192);
        gld16(Bgb + soff0 + k0, db);
        gld16(Bgb + soff1 + k0, db + 8192);
    }
    asm volatile("s_waitcnt vmcnt(8)" ::: "memory");
    __builtin_amdgcn_s_barrier();

    for (int t = 0; t < NT; ++t) {
        const int slot = t & 3;
        const char* Asl = lds + slot * 16384;
        const char* Bsl = lds + 65536 + slot * 16384;
        const bool pf = (t + 3) < NT;
        const int pk0 = (t + 3) << 5;
        char* pda = lds + ((t + 3) & 3) * 16384 + wid * 1024;
        char* pdb = pda + 65536;

        s16x8 afv[4], bfv[4];
        // ---- phase 0: reads (af0..3, bf0..3) + stage A(t+3)
        #pragma unroll
        for (int mf = 0; mf < 4; ++mf) {
            const int r = wr * 128 + mf * 16 + lq;
            afv[mf] = *(const s16x8*)(Asl + r * 64 + (((lg ^ (r ^ (r >> 2))) & 3) << 4));
        }
        #pragma unroll
        for (int nf = 0; nf < 4; ++nf) {
            const int c = wc * 64 + nf * 16 + lq;
            bfv[nf] = *(const s16x8*)(Bsl + c * 64 + (((lg ^ (c ^ (c >> 2))) & 3) << 4));
        }
        if (pf) {
            gld16(Agb + soff0 + pk0, pda);
            gld16(Agb + soff1 + pk0, pda + 8192);
        }
        __builtin_amdgcn_s_barrier();
        __builtin_amdgcn_s_setprio(1);
        #pragma unroll
        for (int mf = 0; mf < 4; ++mf)
            #pragma unroll
            for (int nf = 0; nf < 4; ++nf)
                acc[mf][nf] = __builtin_amdgcn_mfma_f32_16x16x32_bf16(
                    afv[mf], bfv[nf], acc[mf][nf], 0, 0, 0);
        __builtin_amdgcn_s_setprio(0);
        __builtin_amdgcn_s_barrier();

        // ---- phase 1: reads (af4..7) + stage B(t+3)
        #pragma unroll
        for (int mf = 0; mf < 4; ++mf) {
            const int r = wr * 128 + (mf + 4) * 16 + lq;
            afv[mf] = *(const s16x8*)(Asl + r * 64 + (((lg ^ (r ^ (r >> 2))) & 3) << 4));
        }
        if (pf) {
            gld16(Bgb + soff0 + pk0, pdb);
            gld16(Bgb + soff1 + pk0, pdb + 8192);
        }
        __builtin_amdgcn_s_barrier();
        __builtin_amdgcn_s_setprio(1);
        #pragma unroll
        for (int mf = 0; mf < 4; ++mf)
            #pragma unroll
            for (int nf = 0; nf < 4; ++nf)
                acc[mf + 4][nf] = __builtin_amdgcn_mfma_f32_16x16x32_bf16(
                    afv[mf], bfv[nf], acc[mf + 4][nf], 0, 0, 0);
        __builtin_amdgcn_s_setprio(0);

        // ---- tile end: counted wait (never 0 until tail)
        const int rem = NT - 2 - t;
        if (rem >= 2)      asm volatile("s_waitcnt vmcnt(8)" ::: "memory");
        else if (rem == 1) asm volatile("s_waitcnt vmcnt(4)" ::: "memory");
        else               asm volatile("s_waitcnt vmcnt(0)" ::: "memory");
        __builtin_amdgcn_s_barrier();
    }

    // ---- epilogue: f32 + bias
    const int lr = l >> 4;
    #pragma unroll
    for (int nf = 0; nf < 4; ++nf) {
        const int gcol = bn + wc * 64 + nf * 16 + lq;
        const float bb = bias[gcol];
        #pragma unroll
        for (int mf = 0; mf < 8; ++mf)
            #pragma unroll
            for (int rg = 0; rg < 4; ++rg) {
                const int grow = brow + wr * 128 + mf * 16 + lr * 4 + rg;
                C[(size_t)grow * N + gcol] = acc[mf][nf][rg] + bb;
            }
    }
}

// ---------------------------------------------------------------------------
// Fallback GEMM (fp32 B in [K][N]) — only if ws can't hold transposed Wout.
// ---------------------------------------------------------------------------
__global__ __launch_bounds__(256) void gemm_f32b(
    const unsigned short* __restrict__ A, const float* __restrict__ B,
    const float* __restrict__ bias, float* __restrict__ C, int N, int K)
{
    __shared__ unsigned short As[8192];
    __shared__ unsigned short Bs[8192];
    const int tid = threadIdx.x;
    const int l   = tid & 63, wid = tid >> 6;
    const int wr  = wid >> 1, wc = wid & 1;
    const int brow = blockIdx.y * 128, bn = blockIdx.x * 128;
    f32x4 acc[4][4];
    #pragma unroll
    for (int i = 0; i < 4; ++i)
        #pragma unroll
        for (int j = 0; j < 4; ++j) acc[i][j] = (f32x4)0.f;
    const int arow = tid >> 3;
    const int aq   = (tid & 7) ^ (arow & 7);
    const int bkq  = tid >> 5, bnq = tid & 31;
    for (int k0 = 0; k0 < K; k0 += 64) {
        #pragma unroll
        for (int r = 0; r < 4; ++r)
            gld16(A + (size_t)(brow + r * 32 + arow) * K + k0 + aq * 8,
                  (char*)As + r * 4096 + wid * 1024);
        #pragma unroll
        for (int r = 0; r < 2; ++r) {
            const int kb = r * 32 + bkq * 4;
            const float* pp = B + (size_t)(k0 + kb) * N + bn + bnq * 4;
            const float4 v0 = *(const float4*)(pp);
            const float4 v1 = *(const float4*)(pp + N);
            const float4 v2 = *(const float4*)(pp + 2 * (size_t)N);
            const float4 v3 = *(const float4*)(pp + 3 * (size_t)N);
            const int g = kb >> 3, bytek = (kb & 4) * 2;
            const float* f0 = (const float*)&v0; const float* f1 = (const float*)&v1;
            const float* f2 = (const float*)&v2; const float* f3 = (const float*)&v3;
            #pragma unroll
            for (int i = 0; i < 4; ++i) {
                const int n = bnq * 4 + i;
                char* dst = (char*)Bs + n * 128 + ((g ^ (n & 7)) * 16) + bytek;
                *(u32x2*)dst = (u32x2){pack2(f0[i], f1[i]), pack2(f2[i], f3[i])};
            }
        }
        __syncthreads();
        #pragma unroll
        for (int kk = 0; kk < 2; ++kk) {
            s16x8 af[4], bf[4];
            #pragma unroll
            for (int mf = 0; mf < 4; ++mf) {
                const int row = wr * 64 + mf * 16 + (l & 15);
                const int gg  = (kk * 4 + (l >> 4)) ^ (row & 7);
                af[mf] = *(const s16x8*)((const char*)As + row * 128 + gg * 16);
            }
            #pragma unroll
            for (int nf = 0; nf < 4; ++nf) {
                const int col = wc * 64 + nf * 16 + (l & 15);
                const int gg  = (kk * 4 + (l >> 4)) ^ (col & 7);
                bf[nf] = *(const s16x8*)((const char*)Bs + col * 128 + gg * 16);
            }
            #pragma unroll
            for (int mf = 0; mf < 4; ++mf)
                #pragma unroll
                for (int nf = 0; nf < 4; ++nf)
                    acc[mf][nf] = __builtin_amdgcn_mfma_f32_16x16x32_bf16(
                        af[mf], bf[nf], acc[mf][nf], 0, 0, 0);
        }
        __syncthreads();
    }
    const int lr = l >> 4, lc = l & 15;
    #pragma unroll
    for (int nf = 0; nf < 4; ++nf) {
        const int gcol = bn + wc * 64 + nf * 16 + lc;
        const float bb = bias[gcol];
        #pragma unroll
        for (int mf = 0; mf < 4; ++mf)
            #pragma unroll
            for (int rg = 0; rg < 4; ++rg) {
                const int grow = brow + wr * 64 + mf * 16 + lr * 4 + rg;
                C[(size_t)grow * N + gcol] = acc[mf][nf][rg] + bb;
            }
    }
}

// ---------------------------------------------------------------------------
// Flash attention (unchanged). q,k: bf16 [M][768]; vt: [B][H][64][S].
// ---------------------------------------------------------------------------
__global__ __launch_bounds__(256) void fattn_kernel(
    const unsigned short* __restrict__ qm, const unsigned short* __restrict__ km,
    const unsigned short* __restrict__ vt, const int* __restrict__ ign,
    unsigned short* __restrict__ sab)
{
    __shared__ unsigned short Ks[4096];
    __shared__ unsigned short VTs[4096];
    __shared__ int igns[64];
    __shared__ unsigned short PTs[4][1024];

    const int qt = blockIdx.x, hh = blockIdx.y, b = blockIdx.z;
    const int tid = threadIdx.x;
    const int l = tid & 63, w = tid >> 6;
    const int g = l >> 4, lq = l & 15;
    const int i = qt * 64 + w * 16 + lq;

    const size_t qgb = ((size_t)(b * S_ + i)) * D_ + hh * 64;
    const s16x8 qf0 = *(const s16x8*)(qm + qgb + g * 8);
    const s16x8 qf1 = *(const s16x8*)(qm + qgb + 32 + g * 8);

    f32x4 accO[4];
    #pragma unroll
    for (int d = 0; d < 4; ++d) accO[d] = (f32x4)0.f;
    float mrun = -1e30f, lrun = 0.f;

    const int srow = tid >> 3, sg = tid & 7;

    for (int t = 0; t <= qt; ++t) {
        const int j0 = t * 64;
        #pragma unroll
        for (int r = 0; r < 2; ++r) {
            const int row = r * 32 + srow;
            const int gsw = (sg ^ (row & 7)) * 8;
            gld16(km + (size_t)(b * S_ + j0 + row) * D_ + hh * 64 + gsw,
                  (char*)Ks + (r * 256 + tid) * 16);
            gld16(vt + ((size_t)(b * H_ + hh) * 64 + row) * S_ + j0 + gsw,
                  (char*)VTs + (r * 256 + tid) * 16);
        }
        if (tid < 64) igns[tid] = ign[b * S_ + j0 + tid];
        __syncthreads();

        f32x4 sacc[4];
        #pragma unroll
        for (int kf = 0; kf < 4; ++kf) sacc[kf] = (f32x4)0.f;
        #pragma unroll
        for (int kk = 0; kk < 2; ++kk) {
            const s16x8 qv = kk ? qf1 : qf0;
            #pragma unroll
            for (int kf = 0; kf < 4; ++kf) {
                const int row = kf * 16 + lq;
                const s16x8 kv = *(const s16x8*)((const char*)Ks + row * 128 +
                                                 (((kk * 4 + g) ^ (row & 7)) * 16));
                sacc[kf] = __builtin_amdgcn_mfma_f32_16x16x32_bf16(kv, qv, sacc[kf], 0, 0, 0);
            }
        }

        float tmax = -INFINITY;
        #pragma unroll
        for (int kf = 0; kf < 4; ++kf)
            #pragma unroll
            for (int rg = 0; rg < 4; ++rg) {
                const int j = j0 + kf * 16 + g * 4 + rg;
                float s = sacc[kf][rg] * 0.125f;
                const bool ok = (j <= i) && (igns[kf * 16 + g * 4 + rg] == 0 || j == i);
                s = ok ? s : -INFINITY;
                sacc[kf][rg] = s;
                tmax = fmaxf(tmax, s);
            }
        tmax = fmaxf(tmax, __shfl_xor(tmax, 16));
        tmax = fmaxf(tmax, __shfl_xor(tmax, 32));
        const float mnew = fmaxf(mrun, tmax);
        const float fac = __expf(mrun - mnew);
        float psum = 0.f;
        #pragma unroll
        for (int kf = 0; kf < 4; ++kf)
            #pragma unroll
            for (int rg = 0; rg < 4; ++rg) {
                const float p = __expf(sacc[kf][rg] - mnew);
                sacc[kf][rg] = p;
                psum += p;
            }
        psum += __shfl_xor(psum, 16);
        psum += __shfl_xor(psum, 32);
        lrun = lrun * fac + psum;
        mrun = mnew;
        #pragma unroll
        for (int d = 0; d < 4; ++d) accO[d] *= fac;

        char* ptw = (char*)&PTs[w][0];
        #pragma unroll
        for (int kf = 0; kf < 4; ++kf) {
            u32x2 pk;
            pk[0] = pack2(sacc[kf][0], sacc[kf][1]);
            pk[1] = pack2(sacc[kf][2], sacc[kf][3]);
            *(u32x2*)(ptw + lq * 128 +
                      (((kf * 2 + (g >> 1)) ^ (lq & 7)) * 16) + (g & 1) * 8) = pk;
        }
        #pragma unroll
        for (int kh = 0; kh < 2; ++kh) {
            const s16x8 pb = *(const s16x8*)(ptw + lq * 128 +
                                             (((kh * 4 + g) ^ (lq & 7)) * 16));
            #pragma unroll
            for (int df = 0; df < 4; ++df) {
                const int row = df * 16 + lq;
                const s16x8 vf = *(const s16x8*)((const char*)VTs + row * 128 +
                                                 (((kh * 4 + g) ^ (row & 7)) * 16));
                accO[df] = __builtin_amdgcn_mfma_f32_16x16x32_bf16(vf, pb, accO[df], 0, 0, 0);
            }
        }
        __syncthreads();
    }

    const float inv = 1.0f / lrun;
    unsigned short* orow = sab + ((size_t)(b * S_ + i)) * D_ + hh * 64;
    #pragma unroll
    for (int df = 0; df < 4; ++df) {
        u32x2 pk;
        pk[0] = pack2(accO[df][0] * inv, accO[df][1] * inv);
        pk[1] = pack2(accO[df][2] * inv, accO[df][3] * inv);
        *(u32x2*)(orow + df * 16 + g * 4) = pk;
    }
}

// ---------------------------------------------------------------------------
__global__ __launch_bounds__(256) void embed_kernel(
    const int* __restrict__ x, const int* __restrict__ ign,
    const float* __restrict__ emb, const float* __restrict__ pos,
    float* __restrict__ h, unsigned short* __restrict__ hbf)
{
    const int row = blockIdx.x;
    const int s = row & (S_ - 1);
    const int tok = x[row];
    const float keep = (ign[row] == 0) ? 1.0f : 0.0f;
    const float* er = emb + (size_t)tok * D_;
    const float* pr = pos + (size_t)s * D_;
    float* hr = h + (size_t)row * D_;
    unsigned short* hb = hbf + (size_t)row * D_;
    for (int d = threadIdx.x; d < D_; d += 256) {
        const float t = er[d] + pr[d] * keep;
        hr[d] = t;
        hb[d] = f2bf(t);
    }
}

// ---------------------------------------------------------------------------
__global__ __launch_bounds__(256) void add_ln_kernel(
    const float* __restrict__ X, const float* __restrict__ Y,
    float* __restrict__ out, unsigned short* __restrict__ outbf)
{
    const int row = blockIdx.x;
    const int tid = threadIdx.x;
    __shared__ float buf[D_];
    __shared__ float red[256];
    const float* xr = X + (size_t)row * D_;
    const float* yr = Y + (size_t)row * D_;
    float s0 = 0.f;
    for (int d = tid; d < D_; d += 256) {
        const float t = xr[d] + yr[d];
        buf[d] = t;
        s0 += t;
    }
    red[tid] = s0; __syncthreads();
    for (int o = 128; o; o >>= 1) {
        if (tid < o) red[tid] += red[tid + o];
        __syncthreads();
    }
    const float mu = red[0] * (1.0f / D_);
    __syncthreads();
    float s1 = 0.f;
    for (int d = tid; d < D_; d += 256) {
        const float t = buf[d] - mu;
        s1 += t * t;
    }
    red[tid] = s1; __syncthreads();
    for (int o = 128; o; o >>= 1) {
        if (tid < o) red[tid] += red[tid + o];
        __syncthreads();
    }
    const float inv = 1.0f / sqrtf(red[0] * (1.0f / D_));
    float* orow = out + (size_t)row * D_;
    unsigned short* obf = outbf + (size_t)row * D_;
    for (int d = tid; d < D_; d += 256) {
        const float t = (buf[d] - mu) * inv;
        orow[d] = t;
        obf[d] = f2bf(t);
    }
}

// ---------------------------------------------------------------------------
extern "C" void kernel_launch(void* const* d_in, const int* in_sizes, int n_in,
                              void* d_out, int out_size, void* d_ws, size_t ws_size,
                              hipStream_t stream)
{
    const int*   x    = (const int*)d_in[0];
    const int*   ign  = (const int*)d_in[1];
    const float* emb  = (const float*)d_in[2];
    const float* pos  = (const float*)d_in[3];
    const float* Wq   = (const float*)d_in[4];
    const float* bq   = (const float*)d_in[5];
    const float* Wk   = (const float*)d_in[6];
    const float* bk   = (const float*)d_in[7];
    const float* Wv   = (const float*)d_in[8];
    const float* bv   = (const float*)d_in[9];
    const float* Wo   = (const float*)d_in[10];
    const float* bo   = (const float*)d_in[11];
    const float* W1   = (const float*)d_in[12];
    const float* b1   = (const float*)d_in[13];
    const float* W2   = (const float*)d_in[14];
    const float* b2   = (const float*)d_in[15];
    const float* Wout = (const float*)d_in[16];
    const float* bout = (const float*)d_in[17];
    float* outp = (float*)d_out;

    const size_t RC = (size_t)M_ * D_;        // 1572864
    const size_t F1 = (size_t)M_ * DH_;       // 6291456
    const size_t WH = (size_t)H_ * 64 * D_;   // 589824
    const size_t WF = (size_t)D_ * DH_;       // 2359296
    const size_t WOUTE = (size_t)V_ * D_;     // 24576000

    char* wsp = (char*)d_ws;
    size_t wsleft = ws_size;
    char* dop = (char*)d_out;
    auto alloc = [&](size_t bytes, bool must_ws) -> void* {
        bytes = (bytes + 255) & ~(size_t)255;
        if (wsleft >= bytes) { void* p = wsp; wsp += bytes; wsleft -= bytes; return p; }
        if (must_ws) return nullptr;
        void* p = dop; dop += bytes; return p;
    };

    unsigned short* hbf   = (unsigned short*)alloc(RC * 2, true);
    unsigned short* woutT = (unsigned short*)alloc(WOUTE * 2, true);
    float* h   = (float*)alloc(RC * 4, false);
    float* z   = (float*)alloc(RC * 4, false);
    float* tmp = (float*)alloc(RC * 4, false);
    unsigned short* zbf   = (unsigned short*)alloc(RC * 2, false);
    unsigned short* sabbf = (unsigned short*)alloc(RC * 2, false);
    unsigned short* qbf   = (unsigned short*)alloc(RC * 2, false);
    unsigned short* kbf   = (unsigned short*)alloc(RC * 2, false);
    unsigned short* vtb   = (unsigned short*)alloc(RC * 2, false);
    unsigned short* f1bf  = (unsigned short*)alloc(F1 * 2, false);
    unsigned short* wqT = (unsigned short*)alloc(L_ * WH * 2, false);
    unsigned short* wkT = (unsigned short*)alloc(L_ * WH * 2, false);
    unsigned short* wvT = (unsigned short*)alloc(L_ * WH * 2, false);
    unsigned short* woT = (unsigned short*)alloc(L_ * WH * 2, false);
    unsigned short* w1T = (unsigned short*)alloc(L_ * WF * 2, false);
    unsigned short* w2T = (unsigned short*)alloc(L_ * WF * 2, false);

    embed_kernel<<<M_, 256, 0, stream>>>(x, ign, emb, pos, h, hbf);

    for (int l = 0; l < L_; ++l) {
        wtr_kernel<<<dim3(1, 12, H_), 256, 0, stream>>>(Wq + l * WH, wqT + l * WH, D_, 64);
        wtr_kernel<<<dim3(1, 12, H_), 256, 0, stream>>>(Wk + l * WH, wkT + l * WH, D_, 64);
        wtr_kernel<<<dim3(1, 12, H_), 256, 0, stream>>>(Wv + l * WH, wvT + l * WH, D_, 64);
        wtr_kernel<<<dim3(12, 12, 1), 256, 0, stream>>>(Wo + l * WH, woT + l * WH, D_, D_);
        wtr_kernel<<<dim3(48, 12, 1), 256, 0, stream>>>(W1 + l * WF, w1T + l * WF, D_, DH_);
        wtr_kernel<<<dim3(12, 48, 1), 256, 0, stream>>>(W2 + l * WF, w2T + l * WF, DH_, D_);
    }
    if (woutT)
        wtr_kernel<<<dim3(V_ / 64, 12, 1), 256, 0, stream>>>(Wout, woutT, D_, V_);

    for (int l = 0; l < L_; ++l) {
        gemm_qkv3<<<dim3(6, 16, 3), 256, 0, stream>>>(
            hbf, wqT + l * WH, wkT + l * WH, wvT + l * WH,
            bq + l * 768, bk + l * 768, bv + l * 768, qbf, kbf, vtb);

        fattn_kernel<<<dim3(S_ / 64, H_, B_), 256, 0, stream>>>(
            qbf, kbf, vtb, ign, sabbf);

        gemm_bt<<<dim3(6, 16), 256, 0, stream>>>(
            sabbf, woT + l * WH, bo + l * D_, tmp, D_, D_, 0);
        add_ln_kernel<<<M_, 256, 0, stream>>>(h, tmp, z, zbf);

        gemm_bt<<<dim3(24, 16), 256, 0, stream>>>(
            zbf, w1T + l * WF, b1 + l * DH_, f1bf, DH_, D_, 2);
        gemm_bt<<<dim3(6, 16), 256, 0, stream>>>(
            f1bf, w2T + l * WF, b2 + l * D_, tmp, D_, DH_, 1);
        add_ln_kernel<<<M_, 256, 0, stream>>>(z, tmp, h, hbf);
    }

    if (woutT)
        gemm_bt256<<<dim3(V_ / 256, M_ / 256), 512, 0, stream>>>(
            hbf, woutT, bout, outp, V_, D_);
    else
        gemm_f32b<<<dim3(V_ / 128, M_ / 128), 256, 0, stream>>>(
            hbf, Wout, bout, outp, V_, D_);
}